// Round 4
// baseline (459.289 us; speedup 1.0000x reference)
//
#include <hip/hip_runtime.h>
#include <math.h>

// ---------------------------------------------------------------------------
// VQVAE forward, fp32 end-to-end. v4: conv2 16co/wave (LDS-pipe halved),
// fused coalesced prep, pool+proj fused, loss folded into dproj.
// ---------------------------------------------------------------------------

// ---------- fused prep: A aggregation (blocks 0..127) + all transposes ------
__global__ __launch_bounds__(256) void k_prep(const float* __restrict__ w2,
                                              const float* __restrict__ w1,
                                              const float* __restrict__ wp,
                                              const float* __restrict__ wd,
                                              const float* __restrict__ wd1,
                                              const float* __restrict__ cb,
                                              float* __restrict__ w2t,
                                              float* __restrict__ w1t,
                                              float* __restrict__ wpT,
                                              float* __restrict__ wdT,
                                              float* __restrict__ cbT,
                                              float* __restrict__ A) {
  int bx = blockIdx.x, tid = threadIdx.x;
  if (bx < 128) {
    // A[pq][ci][co] for co = bx.  Coalesced read of wd1 row, scattered writes.
    __shared__ float wrow[1152];
    int co = bx;
    for (int i = tid; i < 1152; i += 256) wrow[i] = wd1[co * 1152 + i];
    __syncthreads();
    if (tid < 128) {
      int ci = tid;
      float w[9];
#pragma unroll
      for (int t = 0; t < 9; t++) w[t] = wrow[ci * 9 + t];
      // x-mask sums: {kx0},{kx1,2},{all},{kx0,1},{kx2}
      float rx[3][5];
#pragma unroll
      for (int ky = 0; ky < 3; ky++) {
        float a0 = w[ky * 3 + 0], a1 = w[ky * 3 + 1], a2 = w[ky * 3 + 2];
        rx[ky][0] = a0;
        rx[ky][1] = a1 + a2;
        rx[ky][2] = a0 + a1 + a2;
        rx[ky][3] = a0 + a1;
        rx[ky][4] = a2;
      }
#pragma unroll
      for (int px = 0; px < 5; px++) {
        float s0 = rx[0][px], s1 = rx[1][px], s2 = rx[2][px];
        float ry[5];
        ry[0] = s0; ry[1] = s1 + s2; ry[2] = s0 + s1 + s2; ry[3] = s0 + s1; ry[4] = s2;
#pragma unroll
        for (int py = 0; py < 5; py++)
          A[(py * 5 + px) * 16384 + ci * 128 + co] = ry[py];
      }
    }
    return;
  }
  // transposes: coalesced reads, scattered writes
  int i = (bx - 128) * 256 + tid;
  if (i < 147456) {              // w2t[k][co] = w2[co][k]
    int co = i / 1152, k = i - co * 1152;
    w2t[k * 128 + co] = w2[i];
  } else if (i < 150912) {       // w1t[t][co] = w1[co][t]
    int j = i - 147456;
    int co = j / 27, t = j - co * 27;
    w1t[t * 128 + co] = w1[j];
  } else if (i < 159104) {       // wpT[k][d] = wp[d][k]
    int j = i - 150912;
    int d = j >> 7, k = j & 127;
    wpT[k * 64 + d] = wp[j];
  } else if (i < 167296) {       // wdT[d][co] = wd[co][d]
    int j = i - 159104;
    int co = j >> 6, d = j & 63;
    wdT[d * 128 + co] = wd[j];
  } else if (i < 200064) {       // cbT[d][k] = cb[k][d]
    int j = i - 167296;
    int k = j >> 6, d = j & 63;
    cbT[d * 512 + k] = cb[j];
  }
}

// ---------- conv1: (32,3,128,128) -> (32,128,64,64), 3x3 s2 p1, relu ----------
// grid (4 co_t, 16 oh_t, 32 b), block 256. Wave owns 8 co; lane = 4 ow x 1 oh.
__global__ __launch_bounds__(256) void k_conv1(const float* __restrict__ x,
                                               const float* __restrict__ w1t,
                                               const float* __restrict__ b1,
                                               float* __restrict__ h1) {
  __shared__ float E[3][9][68];
  __shared__ float O[3][9][68];
  int co_t = blockIdx.x, oh_t = blockIdx.y, b = blockIdx.z;
  int oh0 = oh_t * 4;
  int tid = threadIdx.x;
  int wv = __builtin_amdgcn_readfirstlane(tid >> 6);
  int l = tid & 63;
  int coB = co_t * 32 + wv * 8;

  for (int idx = tid; idx < 1728; idx += 256) {
    int p = idx & 63, r = idx >> 6;
    int ci = r / 9, lr = r - ci * 9;
    int ih = 2 * oh0 - 1 + lr;
    float2 v = make_float2(0.f, 0.f);
    if ((unsigned)ih < 128u)
      v = *(const float2*)&x[((b * 3 + ci) * 128 + ih) * 128 + 2 * p];
    E[ci][lr][p] = v.x;
    O[ci][lr][p + 1] = v.y;
  }
  if (tid < 27) {
    int ci = tid / 9, lr = tid - ci * 9;
    O[ci][lr][0] = 0.f;
  }
  __syncthreads();

  int ohl = l >> 4, ow0 = (l & 15) * 4;
  int oh = oh0 + ohl;
  float4 acc[8];
#pragma unroll
  for (int q = 0; q < 8; q++) {
    float bv = b1[coB + q];
    acc[q] = make_float4(bv, bv, bv, bv);
  }
#pragma unroll
  for (int ci = 0; ci < 3; ci++) {
#pragma unroll
    for (int ky = 0; ky < 3; ky++) {
      int lr = 2 * ohl + ky;
      float4 ev = *(float4*)&E[ci][lr][ow0];
      float4 od = *(float4*)&O[ci][lr][ow0];
      float o4 = O[ci][lr][ow0 + 4];
      const float* wr = w1t + (ci * 9 + ky * 3) * 128 + coB;
#pragma unroll
      for (int q = 0; q < 8; q++) {
        float wa = wr[q], wb = wr[128 + q], wc = wr[256 + q];
        acc[q].x = fmaf(wa, od.x, acc[q].x);
        acc[q].x = fmaf(wb, ev.x, acc[q].x);
        acc[q].x = fmaf(wc, od.y, acc[q].x);
        acc[q].y = fmaf(wa, od.y, acc[q].y);
        acc[q].y = fmaf(wb, ev.y, acc[q].y);
        acc[q].y = fmaf(wc, od.z, acc[q].y);
        acc[q].z = fmaf(wa, od.z, acc[q].z);
        acc[q].z = fmaf(wb, ev.z, acc[q].z);
        acc[q].z = fmaf(wc, od.w, acc[q].z);
        acc[q].w = fmaf(wa, od.w, acc[q].w);
        acc[q].w = fmaf(wb, ev.w, acc[q].w);
        acc[q].w = fmaf(wc, o4,   acc[q].w);
      }
    }
  }
#pragma unroll
  for (int q = 0; q < 8; q++) {
    float4 r4;
    r4.x = fmaxf(acc[q].x, 0.f);
    r4.y = fmaxf(acc[q].y, 0.f);
    r4.z = fmaxf(acc[q].z, 0.f);
    r4.w = fmaxf(acc[q].w, 0.f);
    *(float4*)&h1[((b * 128 + coB + q) * 64 + oh) * 64 + ow0] = r4;
  }
}

// ---------- conv2: (32,128,64,64) -> (32,128,32,32), 3x3 s2 p1, relu ----------
// grid (2 co_t, 8 oh_t, 32 b) = 512 blocks. Wave owns 16 co; lane = 2 ow x 1 oh.
__global__ __launch_bounds__(256) void k_conv2(const float* __restrict__ h1,
                                               const float* __restrict__ w2t,
                                               const float* __restrict__ b2,
                                               float* __restrict__ h2) {
  __shared__ float E[8][9][36];
  __shared__ float O[8][9][36];
  int co_t = blockIdx.x, oh_t = blockIdx.y, b = blockIdx.z;
  int oh0 = oh_t * 4;
  int tid = threadIdx.x;
  int wv = __builtin_amdgcn_readfirstlane(tid >> 6);
  int l = tid & 63;
  int coB = co_t * 64 + wv * 16;
  int ohl = l >> 4, ow0 = (l & 15) * 2;
  int oh = oh0 + ohl;

  float2 acc[16];
#pragma unroll
  for (int q = 0; q < 16; q++) {
    float bv = b2[coB + q];
    acc[q] = make_float2(bv, bv);
  }

  for (int ci0 = 0; ci0 < 128; ci0 += 8) {
    __syncthreads();
    for (int idx = tid; idx < 2304; idx += 256) {  // 8ci*9lr*32p
      int p = idx & 31, r = idx >> 5;
      int ci = r & 7, lr = r >> 3;
      int ih = 2 * oh0 - 1 + lr;
      float2 v = make_float2(0.f, 0.f);
      if ((unsigned)ih < 64u)
        v = *(const float2*)&h1[((b * 128 + ci0 + ci) * 64 + ih) * 64 + 2 * p];
      E[ci][lr][p] = v.x;
      O[ci][lr][p + 1] = v.y;
    }
    if (tid < 72) {
      int ci = tid & 7, lr = tid >> 3;
      O[ci][lr][0] = 0.f;
    }
    __syncthreads();

    for (int ci = 0; ci < 8; ci++) {
#pragma unroll
      for (int ky = 0; ky < 3; ky++) {
        int lr = 2 * ohl + ky;
        float2 ev = *(float2*)&E[ci][lr][ow0];
        float2 od = *(float2*)&O[ci][lr][ow0];
        float o2 = O[ci][lr][ow0 + 2];
        int k = (ci0 + ci) * 9 + ky * 3;
#pragma unroll
        for (int g = 0; g < 2; g++) {  // two 8-co groups: bounded SGPR liveness
          const float* wr = w2t + k * 128 + coB + g * 8;
#pragma unroll
          for (int q = 0; q < 8; q++) {
            float wa = wr[q], wb = wr[128 + q], wc = wr[256 + q];
            float2* a = &acc[g * 8 + q];
            a->x = fmaf(wa, od.x, a->x);
            a->x = fmaf(wb, ev.x, a->x);
            a->x = fmaf(wc, od.y, a->x);
            a->y = fmaf(wa, od.y, a->y);
            a->y = fmaf(wb, ev.y, a->y);
            a->y = fmaf(wc, o2,   a->y);
          }
        }
      }
    }
  }
#pragma unroll
  for (int q = 0; q < 16; q++) {
    float2 r2 = make_float2(fmaxf(acc[q].x, 0.f), fmaxf(acc[q].y, 0.f));
    *(float2*)&h2[((b * 128 + coB + q) * 32 + oh) * 32 + ow0] = r2;
  }
}

// ---------- pool(4x4 mean) + proj(1x1,128->64) fused; grid 32 (b) -----------
__global__ __launch_bounds__(256) void k_poolproj(const float* __restrict__ h2,
                                                  const float* __restrict__ wpT,
                                                  const float* __restrict__ pb,
                                                  float* __restrict__ z_e_out) {
  __shared__ float hp[128][64];
  __shared__ float Ws[128][64];
  int b = blockIdx.x, tid = threadIdx.x;
  for (int i = tid; i < 8192; i += 256) Ws[i >> 6][i & 63] = wpT[i];
  for (int i = tid; i < 8192; i += 256) {
    int ci = i >> 6, pi = i & 63;
    int bi = pi >> 3, bj = pi & 7;
    const float* src = &h2[((b * 128 + ci) * 32 + bi * 4) * 32 + bj * 4];
    float4 r0 = *(const float4*)src;
    float4 r1 = *(const float4*)(src + 32);
    float4 r2 = *(const float4*)(src + 64);
    float4 r3 = *(const float4*)(src + 96);
    float s = r0.x + r0.y + r0.z + r0.w + r1.x + r1.y + r1.z + r1.w +
              r2.x + r2.y + r2.z + r2.w + r3.x + r3.y + r3.z + r3.w;
    hp[ci][pi] = s * 0.0625f;
  }
  __syncthreads();
  int ty = tid >> 4, tx = tid & 15;
  int d0 = ty * 4, s0 = tx * 4;
  float4 acc[4];
#pragma unroll
  for (int i = 0; i < 4; i++) acc[i] = make_float4(0.f, 0.f, 0.f, 0.f);
  for (int k = 0; k < 128; k++) {
    float4 a = *(float4*)&Ws[k][d0];
    float4 h = *(float4*)&hp[k][s0];
    acc[0].x = fmaf(a.x, h.x, acc[0].x); acc[0].y = fmaf(a.x, h.y, acc[0].y);
    acc[0].z = fmaf(a.x, h.z, acc[0].z); acc[0].w = fmaf(a.x, h.w, acc[0].w);
    acc[1].x = fmaf(a.y, h.x, acc[1].x); acc[1].y = fmaf(a.y, h.y, acc[1].y);
    acc[1].z = fmaf(a.y, h.z, acc[1].z); acc[1].w = fmaf(a.y, h.w, acc[1].w);
    acc[2].x = fmaf(a.z, h.x, acc[2].x); acc[2].y = fmaf(a.z, h.y, acc[2].y);
    acc[2].z = fmaf(a.z, h.z, acc[2].z); acc[2].w = fmaf(a.z, h.w, acc[2].w);
    acc[3].x = fmaf(a.w, h.x, acc[3].x); acc[3].y = fmaf(a.w, h.y, acc[3].y);
    acc[3].z = fmaf(a.w, h.z, acc[3].z); acc[3].w = fmaf(a.w, h.w, acc[3].w);
  }
#pragma unroll
  for (int i = 0; i < 4; i++) {
    float bv = pb[d0 + i];
    float4 r4 = make_float4(acc[i].x + bv, acc[i].y + bv, acc[i].z + bv, acc[i].w + bv);
    *(float4*)&z_e_out[(b * 64 + d0 + i) * 64 + s0] = r4;
  }
}

// ---------- VQ: argmin over 512 codes (coalesced via cbT), loss accum --------
__global__ __launch_bounds__(64) void k_vq(const float* __restrict__ z_e,
                                           const float* __restrict__ cbT,
                                           const float* __restrict__ cb,
                                           float* __restrict__ idx_f,
                                           int* __restrict__ idx_i,
                                           float* __restrict__ loss_acc) {
  __shared__ float zs[64];
  int n = blockIdx.x, lane = threadIdx.x;
  int b = n >> 6, pi = n & 63;
  zs[lane] = z_e[(b * 64 + lane) * 64 + pi];
  __syncthreads();
  double best = 1e300;
  int bi = 0;
#pragma unroll 2
  for (int j = 0; j < 8; j++) {
    int k = j * 64 + lane;
    double acc = 0.0;
#pragma unroll 8
    for (int d = 0; d < 64; d++) {
      float c = cbT[d * 512 + k];
      double diff = (double)zs[d] - (double)c;
      acc = fma(diff, diff, acc);
    }
    if (acc < best) { best = acc; bi = k; }
  }
  for (int m = 1; m < 64; m <<= 1) {
    double ob = __shfl_xor(best, m, 64);
    int oi = __shfl_xor(bi, m, 64);
    if (ob < best || (ob == best && oi < bi)) { best = ob; bi = oi; }
  }
  float e = cb[bi * 64 + lane] - zs[lane];
  float sq = e * e;
  for (int m = 1; m < 64; m <<= 1) sq += __shfl_xor(sq, m, 64);
  if (lane == 0) {
    idx_f[n] = (float)bi;
    idx_i[n] = bi;
    atomicAdd(loss_acc, sq);
  }
}

// ---------- dproj(1x1, 64->128) + relu -> Yr; block 0 also writes loss -------
__global__ __launch_bounds__(128) void k_dproj(const int* __restrict__ idx_i,
                                               const float* __restrict__ cb,
                                               const float* __restrict__ wdT,
                                               const float* __restrict__ db,
                                               float* __restrict__ Yr,
                                               const float* __restrict__ loss_acc,
                                               float* __restrict__ out_loss) {
  __shared__ float zq[64];
  int n = blockIdx.x, tid = threadIdx.x;
  if (n == 0 && tid == 0) out_loss[0] = loss_acc[0] * 1.25f / 131072.0f;
  int b = n >> 6, pi = n & 63;
  int id = idx_i[n];
  if (tid < 64) zq[tid] = cb[id * 64 + tid];
  __syncthreads();
  float acc = db[tid];
#pragma unroll 4
  for (int d = 0; d < 64; d++) acc = fmaf(wdT[d * 128 + tid], zq[d], acc);
  Yr[(b * 128 + tid) * 64 + pi] = fmaxf(acc, 0.f);
}

// ---------- dec: G[pq][n][co] = sum_ci A[pq][ci][co] * Yshift[ci][n] ----------
__global__ __launch_bounds__(256) void k_dec(const float* __restrict__ Yr,
                                             const float* __restrict__ A,
                                             float* __restrict__ G) {
  __shared__ float Bs[16][256];
  int bx = blockIdx.x;
  int co_t = bx & 3, n_t = bx >> 2;
  int pq = blockIdx.y;
  int py = pq / 5, px = pq - py * 5;
  int dy = (py == 0) ? -1 : ((py == 4) ? 1 : 0);
  int dx = (px == 0) ? -1 : ((px == 4) ? 1 : 0);
  int tid = threadIdx.x;
  int wv = __builtin_amdgcn_readfirstlane(tid >> 6);
  int l = tid & 63;
  int coB = co_t * 32 + wv * 8;
  int nB = n_t * 256;

  float4 acc[8];
#pragma unroll
  for (int q = 0; q < 8; q++) acc[q] = make_float4(0.f, 0.f, 0.f, 0.f);

  for (int ci0 = 0; ci0 < 128; ci0 += 16) {
    __syncthreads();
    for (int idx = tid; idx < 4096; idx += 256) {
      int nn = idx & 255, kk = idx >> 8;
      int n = nB + nn;
      int bb = n >> 6, s = n & 63;
      int sy = (s >> 3) + dy, sx = (s & 7) + dx;
      float v = 0.f;
      if ((unsigned)sy < 8u && (unsigned)sx < 8u)
        v = Yr[(bb * 128 + ci0 + kk) * 64 + sy * 8 + sx];
      Bs[kk][nn] = v;
    }
    __syncthreads();
    for (int kk = 0; kk < 16; kk++) {
      float4 bb4 = *(float4*)&Bs[kk][l * 4];
      const float* ar = A + pq * 16384 + (ci0 + kk) * 128 + coB;
#pragma unroll
      for (int q = 0; q < 8; q++) {
        float av = ar[q];
        acc[q].x = fmaf(av, bb4.x, acc[q].x);
        acc[q].y = fmaf(av, bb4.y, acc[q].y);
        acc[q].z = fmaf(av, bb4.z, acc[q].z);
        acc[q].w = fmaf(av, bb4.w, acc[q].w);
      }
    }
  }
  int nbase = nB + l * 4;
#pragma unroll
  for (int j = 0; j < 4; j++) {
    float* gp = &G[(pq * 2048 + nbase + j) * 128 + coB];
    const float* af = (const float*)acc;
    float4 g0 = make_float4(af[0 * 4 + j], af[1 * 4 + j], af[2 * 4 + j], af[3 * 4 + j]);
    float4 g1 = make_float4(af[4 * 4 + j], af[5 * 4 + j], af[6 * 4 + j], af[7 * 4 + j]);
    *(float4*)gp = g0;
    *(float4*)(gp + 4) = g1;
  }
}

// ---------- out: combine G per class, bias+relu, 1x1 conv to 3ch, splat ------
__global__ __launch_bounds__(256) void k_out(const float* __restrict__ G,
                                             const float* __restrict__ bc1,
                                             const float* __restrict__ w3,
                                             const float* __restrict__ b3,
                                             float* __restrict__ xhat) {
  __shared__ float Tb[9][128];
  __shared__ float part[9][3][8];
  __shared__ float vals[9][3];
  int bj = blockIdx.x, bi = blockIdx.y, b = blockIdx.z;
  int s = bi * 8 + bj;
  int n = b * 64 + s;
  int tid = threadIdx.x;
  int co = tid & 127, h = tid >> 7;
  const int rset[3][2] = {{0, 1}, {2, 2}, {3, 4}};
  const int rcnt[3] = {2, 1, 2};
  for (int cls = h; cls < 9; cls += 2) {
    int r = cls / 3, c = cls - r * 3;
    float sum = bc1[co];
    for (int iy = 0; iy < rcnt[r]; iy++) {
      int py = rset[r][iy];
      for (int ix = 0; ix < rcnt[c]; ix++) {
        int px = rset[c][ix];
        sum += G[((py * 5 + px) * 2048 + n) * 128 + co];
      }
    }
    Tb[cls][co] = fmaxf(sum, 0.f);
  }
  __syncthreads();
  if (tid < 216) {
    int cls = tid / 24, rem = tid - cls * 24;
    int cc = rem >> 3, seg = rem & 7;
    float ss = 0.f;
#pragma unroll
    for (int d = 0; d < 16; d++) ss = fmaf(w3[cc * 128 + seg * 16 + d], Tb[cls][seg * 16 + d], ss);
    part[cls][cc][seg] = ss;
  }
  __syncthreads();
  if (tid < 27) {
    int cls = tid / 3, cc = tid - cls * 3;
    float ss = b3[cc];
#pragma unroll
    for (int seg = 0; seg < 8; seg++) ss += part[cls][cc][seg];
    vals[cls][cc] = ss;
  }
  __syncthreads();
  for (int i = tid; i < 768; i += 256) {
    int cc = i >> 8, p = i & 255;
    int ry = p >> 4, rx = p & 15;
    int rcls = (ry == 0) ? 0 : ((ry == 15) ? 2 : 1);
    int ccls = (rx == 0) ? 0 : ((rx == 15) ? 2 : 1);
    xhat[((b * 3 + cc) * 128 + bi * 16 + ry) * 128 + bj * 16 + rx] =
        vals[rcls * 3 + ccls][cc];
  }
}

extern "C" void kernel_launch(void* const* d_in, const int* in_sizes, int n_in,
                              void* d_out, int out_size, void* d_ws, size_t ws_size,
                              hipStream_t stream) {
  const float* x   = (const float*)d_in[0];
  const float* w1  = (const float*)d_in[1];
  const float* b1  = (const float*)d_in[2];
  const float* w2  = (const float*)d_in[3];
  const float* b2  = (const float*)d_in[4];
  const float* wp  = (const float*)d_in[5];
  const float* pb  = (const float*)d_in[6];
  const float* cb  = (const float*)d_in[7];
  const float* wd  = (const float*)d_in[8];
  const float* db  = (const float*)d_in[9];
  const float* wc1 = (const float*)d_in[10];
  const float* bc1 = (const float*)d_in[11];
  const float* wc2 = (const float*)d_in[12];
  const float* bc2 = (const float*)d_in[13];
  float* out = (float*)d_out;
  float* ws  = (float*)d_ws;

  // workspace (floats). h1 region [0,16777216) reused by G/Yr after conv2.
  float* h1      = ws;                    // 16777216
  float* G       = ws;                    // 6553600   (after conv2)
  float* Yr      = ws + 6553600;          // 262144    (after conv2)
  float* h2      = ws + 16777216;         // 4194304
  float* w2t     = ws + 20971520;         // 147456
  float* w1t     = ws + 21118976;         // 3456
  float* wpT     = ws + 21122432;         // 8192
  float* wdT     = ws + 21130624;         // 8192
  float* cbT     = ws + 21138816;         // 32768
  float* A       = ws + 21171584;         // 409600
  int*   idxi    = (int*)(ws + 21581184); // 2048
  float* lossacc = ws + 21583232;         // 1

  float* o_xhat = out;
  float* o_idx  = out + 1572864;
  float* o_loss = out + 1574912;
  float* o_ze   = out + 1574913;

  hipMemsetAsync(lossacc, 0, sizeof(float), stream);
  k_prep<<<dim3(910), 256, 0, stream>>>(w2, w1, wp, wd, wc1, cb,
                                        w2t, w1t, wpT, wdT, cbT, A);
  k_conv1<<<dim3(4, 16, 32), 256, 0, stream>>>(x, w1t, b1, h1);
  k_conv2<<<dim3(2, 8, 32), 256, 0, stream>>>(h1, w2t, b2, h2);
  k_poolproj<<<dim3(32), 256, 0, stream>>>(h2, wpT, pb, o_ze);
  k_vq<<<dim3(2048), 64, 0, stream>>>(o_ze, cbT, cb, o_idx, idxi, lossacc);
  k_dproj<<<dim3(2048), 128, 0, stream>>>(idxi, cb, wdT, db, Yr, lossacc, o_loss);
  k_dec<<<dim3(32, 25), 256, 0, stream>>>(Yr, A, G);
  k_out<<<dim3(8, 8, 32), 256, 0, stream>>>(G, bc1, wc2, bc2, o_xhat);
}

// Round 5
// 379.614 us; speedup vs baseline: 1.2099x; 1.2099x over previous
//
#include <hip/hip_runtime.h>
#include <math.h>

// ---------------------------------------------------------------------------
// VQVAE forward. v5: conv2 as 9-tap f16-split MFMA GEMM (no LDS, no barriers,
// direct global frag loads from channels-last f16 hi/lo h1 planes).
// C = Ah*Bh + Ah*Bl + Al*Bh  (per-product err ~2^-22: below fp32 noise).
// Everything else fp32-exact as R4.
// ---------------------------------------------------------------------------

typedef _Float16 f16x8 __attribute__((ext_vector_type(8)));
typedef float f32x4 __attribute__((ext_vector_type(4)));

#define H1N 16777216  // 32*64*64*128 elements per h1 plane; zero tail at [H1N, H1N+64)

// ---------- prep: A-agg (bx<128), transposes, W f16-split, tails ----------
__global__ __launch_bounds__(256) void k_prep(const float* __restrict__ w2,
                                              const float* __restrict__ w1,
                                              const float* __restrict__ wp,
                                              const float* __restrict__ wd,
                                              const float* __restrict__ wd1,
                                              const float* __restrict__ cb,
                                              float* __restrict__ w1t,
                                              float* __restrict__ wpT,
                                              float* __restrict__ wdT,
                                              float* __restrict__ cbT,
                                              float* __restrict__ A,
                                              _Float16* __restrict__ Wh,
                                              _Float16* __restrict__ Wl,
                                              _Float16* __restrict__ h1h,
                                              _Float16* __restrict__ h1l) {
  int bx = blockIdx.x, tid = threadIdx.x;
  if (bx < 128) {
    __shared__ float wrow[1152];
    int co = bx;
    for (int i = tid; i < 1152; i += 256) wrow[i] = wd1[co * 1152 + i];
    __syncthreads();
    if (tid < 128) {
      int ci = tid;
      float w[9];
#pragma unroll
      for (int t = 0; t < 9; t++) w[t] = wrow[ci * 9 + t];
      float rx[3][5];
#pragma unroll
      for (int ky = 0; ky < 3; ky++) {
        float a0 = w[ky * 3 + 0], a1 = w[ky * 3 + 1], a2 = w[ky * 3 + 2];
        rx[ky][0] = a0; rx[ky][1] = a1 + a2; rx[ky][2] = a0 + a1 + a2;
        rx[ky][3] = a0 + a1; rx[ky][4] = a2;
      }
#pragma unroll
      for (int px = 0; px < 5; px++) {
        float s0 = rx[0][px], s1 = rx[1][px], s2 = rx[2][px];
        float ry[5];
        ry[0] = s0; ry[1] = s1 + s2; ry[2] = s0 + s1 + s2; ry[3] = s0 + s1; ry[4] = s2;
#pragma unroll
        for (int py = 0; py < 5; py++)
          A[(py * 5 + px) * 16384 + ci * 128 + co] = ry[py];
      }
    }
    return;
  }
  int i = (bx - 128) * 256 + tid;
  if (i < 3456) {                      // w1t[t][co] = w1[co][t]
    int co = i / 27, t = i - co * 27;
    w1t[t * 128 + co] = w1[i];
  } else if (i < 11648) {              // wpT[k][d] = wp[d][k]
    int j = i - 3456;
    int d = j >> 7, k = j & 127;
    wpT[k * 64 + d] = wp[j];
  } else if (i < 19840) {              // wdT[d][co] = wd[co][d]
    int j = i - 11648;
    int co = j >> 6, d = j & 63;
    wdT[d * 128 + co] = wd[j];
  } else if (i < 52608) {              // cbT[d][k] = cb[k][d]
    int j = i - 19840;
    int k = j >> 6, d = j & 63;
    cbT[d * 512 + k] = cb[j];
  } else if (i < 200064) {             // W f16-split: Wh/Wl[tap][co][ci]
    int j = i - 52608;                 // j < 147456, w2[co][ci][tap]
    int co = j / 1152, r = j - co * 1152;
    int ci = r / 9, tap = r - ci * 9;
    float x = w2[j];
    _Float16 h = (_Float16)x;
    _Float16 lo = (_Float16)(x - (float)h);
    int o = (tap * 128 + co) * 128 + ci;
    Wh[o] = h;
    Wl[o] = lo;
  } else if (i < 200128) {             // zero tails
    h1h[H1N + (i - 200064)] = (_Float16)0.f;
  } else if (i < 200192) {
    h1l[H1N + (i - 200128)] = (_Float16)0.f;
  }
}

// ---------- conv1: (32,3,128,128) -> h1 f16-split NHWC [b][oh][ow][ci] -------
// grid (4 co_t, 16 oh_t, 32 b), block 256. Wave owns 8 co; lane = 4 ow x 1 oh.
__global__ __launch_bounds__(256) void k_conv1(const float* __restrict__ x,
                                               const float* __restrict__ w1t,
                                               const float* __restrict__ b1,
                                               _Float16* __restrict__ h1h,
                                               _Float16* __restrict__ h1l) {
  __shared__ float E[3][9][68];
  __shared__ float O[3][9][68];
  int co_t = blockIdx.x, oh_t = blockIdx.y, b = blockIdx.z;
  int oh0 = oh_t * 4;
  int tid = threadIdx.x;
  int wv = __builtin_amdgcn_readfirstlane(tid >> 6);
  int l = tid & 63;
  int coB = co_t * 32 + wv * 8;

  for (int idx = tid; idx < 1728; idx += 256) {
    int p = idx & 63, r = idx >> 6;
    int ci = r / 9, lr = r - ci * 9;
    int ih = 2 * oh0 - 1 + lr;
    float2 v = make_float2(0.f, 0.f);
    if ((unsigned)ih < 128u)
      v = *(const float2*)&x[((b * 3 + ci) * 128 + ih) * 128 + 2 * p];
    E[ci][lr][p] = v.x;
    O[ci][lr][p + 1] = v.y;
  }
  if (tid < 27) {
    int ci = tid / 9, lr = tid - ci * 9;
    O[ci][lr][0] = 0.f;
  }
  __syncthreads();

  int ohl = l >> 4, ow0 = (l & 15) * 4;
  int oh = oh0 + ohl;
  float4 acc[8];
#pragma unroll
  for (int q = 0; q < 8; q++) {
    float bv = b1[coB + q];
    acc[q] = make_float4(bv, bv, bv, bv);
  }
#pragma unroll
  for (int ci = 0; ci < 3; ci++) {
#pragma unroll
    for (int ky = 0; ky < 3; ky++) {
      int lr = 2 * ohl + ky;
      float4 ev = *(float4*)&E[ci][lr][ow0];
      float4 od = *(float4*)&O[ci][lr][ow0];
      float o4 = O[ci][lr][ow0 + 4];
      const float* wr = w1t + (ci * 9 + ky * 3) * 128 + coB;
#pragma unroll
      for (int q = 0; q < 8; q++) {
        float wa = wr[q], wb = wr[128 + q], wc = wr[256 + q];
        acc[q].x = fmaf(wa, od.x, acc[q].x);
        acc[q].x = fmaf(wb, ev.x, acc[q].x);
        acc[q].x = fmaf(wc, od.y, acc[q].x);
        acc[q].y = fmaf(wa, od.y, acc[q].y);
        acc[q].y = fmaf(wb, ev.y, acc[q].y);
        acc[q].y = fmaf(wc, od.z, acc[q].y);
        acc[q].z = fmaf(wa, od.z, acc[q].z);
        acc[q].z = fmaf(wb, ev.z, acc[q].z);
        acc[q].z = fmaf(wc, od.w, acc[q].z);
        acc[q].w = fmaf(wa, od.w, acc[q].w);
        acc[q].w = fmaf(wb, ev.w, acc[q].w);
        acc[q].w = fmaf(wc, o4,   acc[q].w);
      }
    }
  }
#pragma unroll
  for (int oi = 0; oi < 4; oi++) {
    f16x8 hv, lv;
#pragma unroll
    for (int q = 0; q < 8; q++) {
      float v = fmaxf(((const float*)&acc[q])[oi], 0.f);
      _Float16 h = (_Float16)v;
      float rem = v - (float)h;
      hv[q] = h;
      lv[q] = (_Float16)rem;
    }
    int base = ((b * 64 + oh) * 64 + (ow0 + oi)) * 128 + coB;
    *(f16x8*)&h1h[base] = hv;
    *(f16x8*)&h1l[base] = lv;
  }
}

// ---------- conv2: f16-split MFMA, 9 shifted GEMMs, no LDS ----------
// 2048 waves: wave tile = 32co x (2oh x 32ow of one b). grid 512 x 256thr.
__global__ __launch_bounds__(256) void k_conv2(const _Float16* __restrict__ h1h,
                                               const _Float16* __restrict__ h1l,
                                               const _Float16* __restrict__ Wh,
                                               const _Float16* __restrict__ Wl,
                                               const float* __restrict__ b2,
                                               float* __restrict__ h2) {
  int wid = blockIdx.x * 4 + (threadIdx.x >> 6);
  int l = threadIdx.x & 63;
  int ln = l & 15, quad = l >> 4;
  int coW = (wid & 3) * 32;
  int nT = wid >> 2;                  // [0,512)
  int b = nT >> 4, oh0 = (nT & 15) * 2;
  int kq = quad * 8;
  f32x4 acc[2][4] = {};               // [cs][s]

  for (int ky = 0; ky < 3; ky++) {
    int ih0 = 2 * oh0 - 1 + ky;       // may be -1 (only when oh0==0, ky==0)
    for (int ci0 = 0; ci0 < 128; ci0 += 32) {
#pragma unroll
      for (int kx = 0; kx < 3; kx++) {
        int tap = ky * 3 + kx;
        const int wbase = (tap * 128 + coW + ln) * 128 + ci0 + kq;
        f16x8 Ah0 = *(const f16x8*)&Wh[wbase];
        f16x8 Al0 = *(const f16x8*)&Wl[wbase];
        f16x8 Ah1 = *(const f16x8*)&Wh[wbase + 2048];  // +16 co
        f16x8 Al1 = *(const f16x8*)&Wl[wbase + 2048];
        f16x8 Bh[4], Bl[4];
#pragma unroll
        for (int s = 0; s < 4; s++) {
          int ih = ih0 + 2 * (s >> 1);
          int owl = (s & 1) * 16 + ln;
          int iw = 2 * owl - 1 + kx;
          int idx = ((b * 64 + ih) * 64 + iw) * 128 + ci0 + kq;
          bool ok = (ih >= 0) && (iw >= 0);
          idx = ok ? idx : H1N;       // zero tail
          Bh[s] = *(const f16x8*)&h1h[idx];
          Bl[s] = *(const f16x8*)&h1l[idx];
        }
#pragma unroll
        for (int cs = 0; cs < 2; cs++) {
          f16x8 ah = cs ? Ah1 : Ah0;
          f16x8 al = cs ? Al1 : Al0;
#pragma unroll
          for (int s = 0; s < 4; s++) {
            acc[cs][s] = __builtin_amdgcn_mfma_f32_16x16x32_f16(al, Bh[s], acc[cs][s], 0, 0, 0);
            acc[cs][s] = __builtin_amdgcn_mfma_f32_16x16x32_f16(ah, Bl[s], acc[cs][s], 0, 0, 0);
            acc[cs][s] = __builtin_amdgcn_mfma_f32_16x16x32_f16(ah, Bh[s], acc[cs][s], 0, 0, 0);
          }
        }
      }
    }
  }
  // epilogue: C row = co (quad*4+reg), col = px (lane&15)
#pragma unroll
  for (int cs = 0; cs < 2; cs++)
#pragma unroll
    for (int s = 0; s < 4; s++) {
      int oh = oh0 + (s >> 1);
      int ow = (s & 1) * 16 + ln;
#pragma unroll
      for (int r = 0; r < 4; r++) {
        int co = coW + cs * 16 + quad * 4 + r;
        h2[((b * 128 + co) * 32 + oh) * 32 + ow] = fmaxf(acc[cs][s][r] + b2[co], 0.f);
      }
    }
}

// ---------- pool(4x4 mean) + proj(1x1,128->64) fused; grid 32 (b) -----------
__global__ __launch_bounds__(256) void k_poolproj(const float* __restrict__ h2,
                                                  const float* __restrict__ wpT,
                                                  const float* __restrict__ pb,
                                                  float* __restrict__ z_e_out,
                                                  float* __restrict__ lossacc) {
  __shared__ float hp[128][64];
  __shared__ float Ws[128][64];
  int b = blockIdx.x, tid = threadIdx.x;
  if (b == 0 && tid == 0) lossacc[0] = 0.f;
  for (int i = tid; i < 8192; i += 256) Ws[i >> 6][i & 63] = wpT[i];
  for (int i = tid; i < 8192; i += 256) {
    int ci = i >> 6, pi = i & 63;
    int bi = pi >> 3, bj = pi & 7;
    const float* src = &h2[((b * 128 + ci) * 32 + bi * 4) * 32 + bj * 4];
    float4 r0 = *(const float4*)src;
    float4 r1 = *(const float4*)(src + 32);
    float4 r2 = *(const float4*)(src + 64);
    float4 r3 = *(const float4*)(src + 96);
    float s = r0.x + r0.y + r0.z + r0.w + r1.x + r1.y + r1.z + r1.w +
              r2.x + r2.y + r2.z + r2.w + r3.x + r3.y + r3.z + r3.w;
    hp[ci][pi] = s * 0.0625f;
  }
  __syncthreads();
  int ty = tid >> 4, tx = tid & 15;
  int d0 = ty * 4, s0 = tx * 4;
  float4 acc[4];
#pragma unroll
  for (int i = 0; i < 4; i++) acc[i] = make_float4(0.f, 0.f, 0.f, 0.f);
  for (int k = 0; k < 128; k++) {
    float4 a = *(float4*)&Ws[k][d0];
    float4 h = *(float4*)&hp[k][s0];
    acc[0].x = fmaf(a.x, h.x, acc[0].x); acc[0].y = fmaf(a.x, h.y, acc[0].y);
    acc[0].z = fmaf(a.x, h.z, acc[0].z); acc[0].w = fmaf(a.x, h.w, acc[0].w);
    acc[1].x = fmaf(a.y, h.x, acc[1].x); acc[1].y = fmaf(a.y, h.y, acc[1].y);
    acc[1].z = fmaf(a.y, h.z, acc[1].z); acc[1].w = fmaf(a.y, h.w, acc[1].w);
    acc[2].x = fmaf(a.z, h.x, acc[2].x); acc[2].y = fmaf(a.z, h.y, acc[2].y);
    acc[2].z = fmaf(a.z, h.z, acc[2].z); acc[2].w = fmaf(a.z, h.w, acc[2].w);
    acc[3].x = fmaf(a.w, h.x, acc[3].x); acc[3].y = fmaf(a.w, h.y, acc[3].y);
    acc[3].z = fmaf(a.w, h.z, acc[3].z); acc[3].w = fmaf(a.w, h.w, acc[3].w);
  }
#pragma unroll
  for (int i = 0; i < 4; i++) {
    float bv = pb[d0 + i];
    float4 r4 = make_float4(acc[i].x + bv, acc[i].y + bv, acc[i].z + bv, acc[i].w + bv);
    *(float4*)&z_e_out[(b * 64 + d0 + i) * 64 + s0] = r4;
  }
}

// ---------- VQ: argmin over 512 codes (coalesced via cbT), loss accum --------
__global__ __launch_bounds__(64) void k_vq(const float* __restrict__ z_e,
                                           const float* __restrict__ cbT,
                                           const float* __restrict__ cb,
                                           float* __restrict__ idx_f,
                                           int* __restrict__ idx_i,
                                           float* __restrict__ loss_acc) {
  __shared__ float zs[64];
  int n = blockIdx.x, lane = threadIdx.x;
  int b = n >> 6, pi = n & 63;
  zs[lane] = z_e[(b * 64 + lane) * 64 + pi];
  __syncthreads();
  double best = 1e300;
  int bi = 0;
#pragma unroll 2
  for (int j = 0; j < 8; j++) {
    int k = j * 64 + lane;
    double acc = 0.0;
#pragma unroll 8
    for (int d = 0; d < 64; d++) {
      float c = cbT[d * 512 + k];
      double diff = (double)zs[d] - (double)c;
      acc = fma(diff, diff, acc);
    }
    if (acc < best) { best = acc; bi = k; }
  }
  for (int m = 1; m < 64; m <<= 1) {
    double ob = __shfl_xor(best, m, 64);
    int oi = __shfl_xor(bi, m, 64);
    if (ob < best || (ob == best && oi < bi)) { best = ob; bi = oi; }
  }
  float e = cb[bi * 64 + lane] - zs[lane];
  float sq = e * e;
  for (int m = 1; m < 64; m <<= 1) sq += __shfl_xor(sq, m, 64);
  if (lane == 0) {
    idx_f[n] = (float)bi;
    idx_i[n] = bi;
    atomicAdd(loss_acc, sq);
  }
}

// ---------- dproj(1x1, 64->128) + relu -> Yr; block 0 also writes loss -------
__global__ __launch_bounds__(128) void k_dproj(const int* __restrict__ idx_i,
                                               const float* __restrict__ cb,
                                               const float* __restrict__ wdT,
                                               const float* __restrict__ db,
                                               float* __restrict__ Yr,
                                               const float* __restrict__ loss_acc,
                                               float* __restrict__ out_loss) {
  __shared__ float zq[64];
  int n = blockIdx.x, tid = threadIdx.x;
  if (n == 0 && tid == 0) out_loss[0] = loss_acc[0] * 1.25f / 131072.0f;
  int b = n >> 6, pi = n & 63;
  int id = idx_i[n];
  if (tid < 64) zq[tid] = cb[id * 64 + tid];
  __syncthreads();
  float acc = db[tid];
#pragma unroll 4
  for (int d = 0; d < 64; d++) acc = fmaf(wdT[d * 128 + tid], zq[d], acc);
  Yr[(b * 128 + tid) * 64 + pi] = fmaxf(acc, 0.f);
}

// ---------- dec: G[pq][n][co] = sum_ci A[pq][ci][co] * Yshift[ci][n] ----------
__global__ __launch_bounds__(256) void k_dec(const float* __restrict__ Yr,
                                             const float* __restrict__ A,
                                             float* __restrict__ G) {
  __shared__ float Bs[16][256];
  int bx = blockIdx.x;
  int co_t = bx & 3, n_t = bx >> 2;
  int pq = blockIdx.y;
  int py = pq / 5, px = pq - py * 5;
  int dy = (py == 0) ? -1 : ((py == 4) ? 1 : 0);
  int dx = (px == 0) ? -1 : ((px == 4) ? 1 : 0);
  int tid = threadIdx.x;
  int wv = __builtin_amdgcn_readfirstlane(tid >> 6);
  int l = tid & 63;
  int coB = co_t * 32 + wv * 8;
  int nB = n_t * 256;

  float4 acc[8];
#pragma unroll
  for (int q = 0; q < 8; q++) acc[q] = make_float4(0.f, 0.f, 0.f, 0.f);

  for (int ci0 = 0; ci0 < 128; ci0 += 16) {
    __syncthreads();
    for (int idx = tid; idx < 4096; idx += 256) {
      int nn = idx & 255, kk = idx >> 8;
      int n = nB + nn;
      int bb = n >> 6, s = n & 63;
      int sy = (s >> 3) + dy, sx = (s & 7) + dx;
      float v = 0.f;
      if ((unsigned)sy < 8u && (unsigned)sx < 8u)
        v = Yr[(bb * 128 + ci0 + kk) * 64 + sy * 8 + sx];
      Bs[kk][nn] = v;
    }
    __syncthreads();
    for (int kk = 0; kk < 16; kk++) {
      float4 bb4 = *(float4*)&Bs[kk][l * 4];
      const float* ar = A + pq * 16384 + (ci0 + kk) * 128 + coB;
#pragma unroll
      for (int q = 0; q < 8; q++) {
        float av = ar[q];
        acc[q].x = fmaf(av, bb4.x, acc[q].x);
        acc[q].y = fmaf(av, bb4.y, acc[q].y);
        acc[q].z = fmaf(av, bb4.z, acc[q].z);
        acc[q].w = fmaf(av, bb4.w, acc[q].w);
      }
    }
  }
  int nbase = nB + l * 4;
#pragma unroll
  for (int j = 0; j < 4; j++) {
    float* gp = &G[(pq * 2048 + nbase + j) * 128 + coB];
    const float* af = (const float*)acc;
    float4 g0 = make_float4(af[0 * 4 + j], af[1 * 4 + j], af[2 * 4 + j], af[3 * 4 + j]);
    float4 g1 = make_float4(af[4 * 4 + j], af[5 * 4 + j], af[6 * 4 + j], af[7 * 4 + j]);
    *(float4*)gp = g0;
    *(float4*)(gp + 4) = g1;
  }
}

// ---------- out: combine G per class, bias+relu, 1x1 conv to 3ch, splat ------
__global__ __launch_bounds__(256) void k_out(const float* __restrict__ G,
                                             const float* __restrict__ bc1,
                                             const float* __restrict__ w3,
                                             const float* __restrict__ b3,
                                             float* __restrict__ xhat) {
  __shared__ float Tb[9][128];
  __shared__ float part[9][3][8];
  __shared__ float vals[9][3];
  int bj = blockIdx.x, bi = blockIdx.y, b = blockIdx.z;
  int s = bi * 8 + bj;
  int n = b * 64 + s;
  int tid = threadIdx.x;
  int co = tid & 127, h = tid >> 7;
  const int rset[3][2] = {{0, 1}, {2, 2}, {3, 4}};
  const int rcnt[3] = {2, 1, 2};
  for (int cls = h; cls < 9; cls += 2) {
    int r = cls / 3, c = cls - r * 3;
    float sum = bc1[co];
    for (int iy = 0; iy < rcnt[r]; iy++) {
      int py = rset[r][iy];
      for (int ix = 0; ix < rcnt[c]; ix++) {
        int px = rset[c][ix];
        sum += G[((py * 5 + px) * 2048 + n) * 128 + co];
      }
    }
    Tb[cls][co] = fmaxf(sum, 0.f);
  }
  __syncthreads();
  if (tid < 216) {
    int cls = tid / 24, rem = tid - cls * 24;
    int cc = rem >> 3, seg = rem & 7;
    float ss = 0.f;
#pragma unroll
    for (int d = 0; d < 16; d++) ss = fmaf(w3[cc * 128 + seg * 16 + d], Tb[cls][seg * 16 + d], ss);
    part[cls][cc][seg] = ss;
  }
  __syncthreads();
  if (tid < 27) {
    int cls = tid / 3, cc = tid - cls * 3;
    float ss = b3[cc];
#pragma unroll
    for (int seg = 0; seg < 8; seg++) ss += part[cls][cc][seg];
    vals[cls][cc] = ss;
  }
  __syncthreads();
  for (int i = tid; i < 768; i += 256) {
    int cc = i >> 8, p = i & 255;
    int ry = p >> 4, rx = p & 15;
    int rcls = (ry == 0) ? 0 : ((ry == 15) ? 2 : 1);
    int ccls = (rx == 0) ? 0 : ((rx == 15) ? 2 : 1);
    xhat[((b * 3 + cc) * 128 + bi * 16 + ry) * 128 + bj * 16 + rx] =
        vals[rcls * 3 + ccls][cc];
  }
}

extern "C" void kernel_launch(void* const* d_in, const int* in_sizes, int n_in,
                              void* d_out, int out_size, void* d_ws, size_t ws_size,
                              hipStream_t stream) {
  const float* x   = (const float*)d_in[0];
  const float* w1  = (const float*)d_in[1];
  const float* b1  = (const float*)d_in[2];
  const float* w2  = (const float*)d_in[3];
  const float* b2  = (const float*)d_in[4];
  const float* wp  = (const float*)d_in[5];
  const float* pb  = (const float*)d_in[6];
  const float* cb  = (const float*)d_in[7];
  const float* wd  = (const float*)d_in[8];
  const float* db  = (const float*)d_in[9];
  const float* wc1 = (const float*)d_in[10];
  const float* bc1 = (const float*)d_in[11];
  const float* wc2 = (const float*)d_in[12];
  const float* bc2 = (const float*)d_in[13];
  float* out = (float*)d_out;
  float* ws  = (float*)d_ws;

  // workspace (floats):
  _Float16* h1h = (_Float16*)(ws);             // 8388640 fl (16777216 + 64 tail ush)
  _Float16* h1l = (_Float16*)(ws + 8388640);   // 8388640 fl
  float* h2     = ws + 16777280;               // 4194304
  _Float16* Wh  = (_Float16*)(ws + 20971584);  // 73728 fl (147456 ush)
  _Float16* Wl  = (_Float16*)(ws + 21045312);  // 73728 fl
  float* w1t    = ws + 21119040;               // 3456
  float* wpT    = ws + 21122496;               // 8192
  float* wdT    = ws + 21130688;               // 8192
  float* cbT    = ws + 21138880;               // 32768
  float* A      = ws + 21171648;               // 409600 -> end 21581248
  // overlays inside dead h1h region (valid after conv2):
  float* G       = ws;                         // 6553600
  float* Yr      = ws + 6553600;               // 262144
  int*   idxi    = (int*)(ws + 6815744);       // 2048
  float* lossacc = ws + 6817792;               // 1

  float* o_xhat = out;
  float* o_idx  = out + 1572864;
  float* o_loss = out + 1574912;
  float* o_ze   = out + 1574913;

  k_prep<<<dim3(910), 256, 0, stream>>>(w2, w1, wp, wd, wc1, cb,
                                        w1t, wpT, wdT, cbT, A, Wh, Wl, h1h, h1l);
  k_conv1<<<dim3(4, 16, 32), 256, 0, stream>>>(x, w1t, b1, h1h, h1l);
  k_conv2<<<dim3(512), 256, 0, stream>>>(h1h, h1l, Wh, Wl, b2, h2);
  k_poolproj<<<dim3(32), 256, 0, stream>>>(h2, wpT, pb, o_ze, lossacc);
  k_vq<<<dim3(2048), 64, 0, stream>>>(o_ze, cbT, cb, o_idx, idxi, lossacc);
  k_dproj<<<dim3(2048), 128, 0, stream>>>(idxi, cb, wdT, db, Yr, lossacc, o_loss);
  k_dec<<<dim3(32, 25), 256, 0, stream>>>(Yr, A, G);
  k_out<<<dim3(8, 8, 32), 256, 0, stream>>>(G, bc1, wc2, bc2, o_xhat);
}

// Round 6
// 363.227 us; speedup vs baseline: 1.2645x; 1.0451x over previous
//
#include <hip/hip_runtime.h>
#include <math.h>

// ---------------------------------------------------------------------------
// VQVAE forward. v6: h1 in group-8 NHWC f16 hi/lo planes (conv1 stores fully
// coalesced, conv2 B-frags direct b128), conv2 retiled to 4096 waves,
// vq+dproj fused. C = Ah*Bh + Ah*Bl + Al*Bh f16-split MFMA.
// ---------------------------------------------------------------------------

typedef _Float16 f16x8 __attribute__((ext_vector_type(8)));
typedef float f32x4 __attribute__((ext_vector_type(4)));

#define H1N 16777216  // elements per h1 plane (16 g * 32 b * 64 * 64 * 8); zero tail after

// ---------- prep: A-agg (bx<128), transposes, W f16-split, tails ----------
__global__ __launch_bounds__(256) void k_prep(const float* __restrict__ w2,
                                              const float* __restrict__ w1,
                                              const float* __restrict__ wp,
                                              const float* __restrict__ wd,
                                              const float* __restrict__ wd1,
                                              const float* __restrict__ cb,
                                              float* __restrict__ w1t,
                                              float* __restrict__ wpT,
                                              float* __restrict__ wdT,
                                              float* __restrict__ cbT,
                                              float* __restrict__ A,
                                              _Float16* __restrict__ Wh,
                                              _Float16* __restrict__ Wl,
                                              _Float16* __restrict__ h1h,
                                              _Float16* __restrict__ h1l) {
  int bx = blockIdx.x, tid = threadIdx.x;
  if (bx < 128) {
    __shared__ float wrow[1152];
    int co = bx;
    for (int i = tid; i < 1152; i += 256) wrow[i] = wd1[co * 1152 + i];
    __syncthreads();
    if (tid < 128) {
      int ci = tid;
      float w[9];
#pragma unroll
      for (int t = 0; t < 9; t++) w[t] = wrow[ci * 9 + t];
      float rx[3][5];
#pragma unroll
      for (int ky = 0; ky < 3; ky++) {
        float a0 = w[ky * 3 + 0], a1 = w[ky * 3 + 1], a2 = w[ky * 3 + 2];
        rx[ky][0] = a0; rx[ky][1] = a1 + a2; rx[ky][2] = a0 + a1 + a2;
        rx[ky][3] = a0 + a1; rx[ky][4] = a2;
      }
#pragma unroll
      for (int px = 0; px < 5; px++) {
        float s0 = rx[0][px], s1 = rx[1][px], s2 = rx[2][px];
        float ry[5];
        ry[0] = s0; ry[1] = s1 + s2; ry[2] = s0 + s1 + s2; ry[3] = s0 + s1; ry[4] = s2;
#pragma unroll
        for (int py = 0; py < 5; py++)
          A[(py * 5 + px) * 16384 + ci * 128 + co] = ry[py];
      }
    }
    return;
  }
  int i = (bx - 128) * 256 + tid;
  if (i < 3456) {                      // w1t[t][co] = w1[co][t]
    int co = i / 27, t = i - co * 27;
    w1t[t * 128 + co] = w1[i];
  } else if (i < 11648) {              // wpT[k][d] = wp[d][k]
    int j = i - 3456;
    int d = j >> 7, k = j & 127;
    wpT[k * 64 + d] = wp[j];
  } else if (i < 19840) {              // wdT[d][co] = wd[co][d]
    int j = i - 11648;
    int co = j >> 6, d = j & 63;
    wdT[d * 128 + co] = wd[j];
  } else if (i < 52608) {              // cbT[d][k] = cb[k][d]
    int j = i - 19840;
    int k = j >> 6, d = j & 63;
    cbT[d * 512 + k] = cb[j];
  } else if (i < 200064) {             // W f16-split: Wh/Wl[tap][co][ci]
    int j = i - 52608;                 // j < 147456, w2[co][ci][tap]
    int co = j / 1152, r = j - co * 1152;
    int ci = r / 9, tap = r - ci * 9;
    float x = w2[j];
    _Float16 h = (_Float16)x;
    _Float16 lo = (_Float16)(x - (float)h);
    int o = (tap * 128 + co) * 128 + ci;
    Wh[o] = h;
    Wl[o] = lo;
  } else if (i < 200128) {             // zero tails
    h1h[H1N + (i - 200064)] = (_Float16)0.f;
  } else if (i < 200192) {
    h1l[H1N + (i - 200128)] = (_Float16)0.f;
  }
}

// ---------- conv1: (32,3,128,128) -> h1 f16-split [g][b][oh][ow][8ci] -------
// grid (4 co_t, 16 oh_t, 32 b), block 256. Wave owns 8 co (= one group).
__global__ __launch_bounds__(256) void k_conv1(const float* __restrict__ x,
                                               const float* __restrict__ w1t,
                                               const float* __restrict__ b1,
                                               _Float16* __restrict__ h1h,
                                               _Float16* __restrict__ h1l) {
  __shared__ float E[3][9][68];
  __shared__ float O[3][9][68];
  int co_t = blockIdx.x, oh_t = blockIdx.y, b = blockIdx.z;
  int oh0 = oh_t * 4;
  int tid = threadIdx.x;
  int wv = __builtin_amdgcn_readfirstlane(tid >> 6);
  int l = tid & 63;
  int coB = co_t * 32 + wv * 8;

  for (int idx = tid; idx < 1728; idx += 256) {
    int p = idx & 63, r = idx >> 6;
    int ci = r / 9, lr = r - ci * 9;
    int ih = 2 * oh0 - 1 + lr;
    float2 v = make_float2(0.f, 0.f);
    if ((unsigned)ih < 128u)
      v = *(const float2*)&x[((b * 3 + ci) * 128 + ih) * 128 + 2 * p];
    E[ci][lr][p] = v.x;
    O[ci][lr][p + 1] = v.y;
  }
  if (tid < 27) {
    int ci = tid / 9, lr = tid - ci * 9;
    O[ci][lr][0] = 0.f;
  }
  __syncthreads();

  int ohl = l >> 4, ow0 = (l & 15) * 4;
  int oh = oh0 + ohl;
  float4 acc[8];
#pragma unroll
  for (int q = 0; q < 8; q++) {
    float bv = b1[coB + q];
    acc[q] = make_float4(bv, bv, bv, bv);
  }
#pragma unroll
  for (int ci = 0; ci < 3; ci++) {
#pragma unroll
    for (int ky = 0; ky < 3; ky++) {
      int lr = 2 * ohl + ky;
      float4 ev = *(float4*)&E[ci][lr][ow0];
      float4 od = *(float4*)&O[ci][lr][ow0];
      float o4 = O[ci][lr][ow0 + 4];
      const float* wr = w1t + (ci * 9 + ky * 3) * 128 + coB;
#pragma unroll
      for (int q = 0; q < 8; q++) {
        float wa = wr[q], wb = wr[128 + q], wc = wr[256 + q];
        acc[q].x = fmaf(wa, od.x, acc[q].x);
        acc[q].x = fmaf(wb, ev.x, acc[q].x);
        acc[q].x = fmaf(wc, od.y, acc[q].x);
        acc[q].y = fmaf(wa, od.y, acc[q].y);
        acc[q].y = fmaf(wb, ev.y, acc[q].y);
        acc[q].y = fmaf(wc, od.z, acc[q].y);
        acc[q].z = fmaf(wa, od.z, acc[q].z);
        acc[q].z = fmaf(wb, ev.z, acc[q].z);
        acc[q].z = fmaf(wc, od.w, acc[q].z);
        acc[q].w = fmaf(wa, od.w, acc[q].w);
        acc[q].w = fmaf(wb, ev.w, acc[q].w);
        acc[q].w = fmaf(wc, o4,   acc[q].w);
      }
    }
  }
  int g = coB >> 3;
  int pbase = ((g * 32 + b) * 64 + oh) * 64;
#pragma unroll
  for (int oi = 0; oi < 4; oi++) {
    f16x8 hv, lv;
#pragma unroll
    for (int q = 0; q < 8; q++) {
      float v = fmaxf(((const float*)&acc[q])[oi], 0.f);
      _Float16 h = (_Float16)v;
      float rem = v - (float)h;
      hv[q] = h;
      lv[q] = (_Float16)rem;
    }
    int base = (pbase + ow0 + oi) * 8;
    *(f16x8*)&h1h[base] = hv;
    *(f16x8*)&h1l[base] = lv;
  }
}

// ---------- conv2: f16-split MFMA, 9 shifted GEMMs, no LDS ----------
// 4096 waves: wave tile = 32co x (1oh x 32ow). grid 1024 x 256thr.
__global__ __launch_bounds__(256) void k_conv2(const _Float16* __restrict__ h1h,
                                               const _Float16* __restrict__ h1l,
                                               const _Float16* __restrict__ Wh,
                                               const _Float16* __restrict__ Wl,
                                               const float* __restrict__ b2,
                                               float* __restrict__ h2) {
  int wid = blockIdx.x * 4 + (threadIdx.x >> 6);
  int l = threadIdx.x & 63;
  int ln = l & 15, quad = l >> 4;
  int coW = (wid & 3) * 32;
  int nT = wid >> 2;                  // [0,1024)
  int b = nT >> 5, oh = nT & 31;
  int kq = quad * 8;
  f32x4 acc[2][2] = {};               // [cs][s]

  for (int ky = 0; ky < 3; ky++) {
    int ih = 2 * oh - 1 + ky;         // -1 only when oh==0, ky==0
    for (int ci0 = 0; ci0 < 128; ci0 += 32) {
      int g8 = ((ci0 >> 3) + quad) * 32 + b;
#pragma unroll
      for (int kx = 0; kx < 3; kx++) {
        int tap = ky * 3 + kx;
        const int wbase = (tap * 128 + coW + ln) * 128 + ci0 + kq;
        f16x8 Ah0 = *(const f16x8*)&Wh[wbase];
        f16x8 Al0 = *(const f16x8*)&Wl[wbase];
        f16x8 Ah1 = *(const f16x8*)&Wh[wbase + 2048];  // +16 co
        f16x8 Al1 = *(const f16x8*)&Wl[wbase + 2048];
        f16x8 Bh[2], Bl[2];
#pragma unroll
        for (int s = 0; s < 2; s++) {
          int iw = 2 * (s * 16 + ln) - 1 + kx;
          int idx = ((g8 * 64 + ih) * 64 + iw) * 8;
          bool ok = (ih >= 0) && (iw >= 0);
          idx = ok ? idx : H1N;       // zero tail
          Bh[s] = *(const f16x8*)&h1h[idx];
          Bl[s] = *(const f16x8*)&h1l[idx];
        }
#pragma unroll
        for (int cs = 0; cs < 2; cs++) {
          f16x8 ah = cs ? Ah1 : Ah0;
          f16x8 al = cs ? Al1 : Al0;
#pragma unroll
          for (int s = 0; s < 2; s++) {
            acc[cs][s] = __builtin_amdgcn_mfma_f32_16x16x32_f16(al, Bh[s], acc[cs][s], 0, 0, 0);
            acc[cs][s] = __builtin_amdgcn_mfma_f32_16x16x32_f16(ah, Bl[s], acc[cs][s], 0, 0, 0);
            acc[cs][s] = __builtin_amdgcn_mfma_f32_16x16x32_f16(ah, Bh[s], acc[cs][s], 0, 0, 0);
          }
        }
      }
    }
  }
  // epilogue: C row = co (quad*4+reg), col = px (lane&15)
#pragma unroll
  for (int cs = 0; cs < 2; cs++)
#pragma unroll
    for (int s = 0; s < 2; s++) {
      int ow = s * 16 + ln;
#pragma unroll
      for (int r = 0; r < 4; r++) {
        int co = coW + cs * 16 + quad * 4 + r;
        h2[((b * 128 + co) * 32 + oh) * 32 + ow] = fmaxf(acc[cs][s][r] + b2[co], 0.f);
      }
    }
}

// ---------- pool(4x4 mean) + proj(1x1,128->64) fused; grid 32 (b) -----------
__global__ __launch_bounds__(256) void k_poolproj(const float* __restrict__ h2,
                                                  const float* __restrict__ wpT,
                                                  const float* __restrict__ pb,
                                                  float* __restrict__ z_e_out,
                                                  float* __restrict__ lossacc) {
  __shared__ float hp[128][64];
  __shared__ float Ws[128][64];
  int b = blockIdx.x, tid = threadIdx.x;
  if (b == 0 && tid == 0) lossacc[0] = 0.f;
  for (int i = tid; i < 8192; i += 256) Ws[i >> 6][i & 63] = wpT[i];
  for (int i = tid; i < 8192; i += 256) {
    int ci = i >> 6, pi = i & 63;
    int bi = pi >> 3, bj = pi & 7;
    const float* src = &h2[((b * 128 + ci) * 32 + bi * 4) * 32 + bj * 4];
    float4 r0 = *(const float4*)src;
    float4 r1 = *(const float4*)(src + 32);
    float4 r2 = *(const float4*)(src + 64);
    float4 r3 = *(const float4*)(src + 96);
    float s = r0.x + r0.y + r0.z + r0.w + r1.x + r1.y + r1.z + r1.w +
              r2.x + r2.y + r2.z + r2.w + r3.x + r3.y + r3.z + r3.w;
    hp[ci][pi] = s * 0.0625f;
  }
  __syncthreads();
  int ty = tid >> 4, tx = tid & 15;
  int d0 = ty * 4, s0 = tx * 4;
  float4 acc[4];
#pragma unroll
  for (int i = 0; i < 4; i++) acc[i] = make_float4(0.f, 0.f, 0.f, 0.f);
  for (int k = 0; k < 128; k++) {
    float4 a = *(float4*)&Ws[k][d0];
    float4 h = *(float4*)&hp[k][s0];
    acc[0].x = fmaf(a.x, h.x, acc[0].x); acc[0].y = fmaf(a.x, h.y, acc[0].y);
    acc[0].z = fmaf(a.x, h.z, acc[0].z); acc[0].w = fmaf(a.x, h.w, acc[0].w);
    acc[1].x = fmaf(a.y, h.x, acc[1].x); acc[1].y = fmaf(a.y, h.y, acc[1].y);
    acc[1].z = fmaf(a.y, h.z, acc[1].z); acc[1].w = fmaf(a.y, h.w, acc[1].w);
    acc[2].x = fmaf(a.z, h.x, acc[2].x); acc[2].y = fmaf(a.z, h.y, acc[2].y);
    acc[2].z = fmaf(a.z, h.z, acc[2].z); acc[2].w = fmaf(a.z, h.w, acc[2].w);
    acc[3].x = fmaf(a.w, h.x, acc[3].x); acc[3].y = fmaf(a.w, h.y, acc[3].y);
    acc[3].z = fmaf(a.w, h.z, acc[3].z); acc[3].w = fmaf(a.w, h.w, acc[3].w);
  }
#pragma unroll
  for (int i = 0; i < 4; i++) {
    float bv = pb[d0 + i];
    float4 r4 = make_float4(acc[i].x + bv, acc[i].y + bv, acc[i].z + bv, acc[i].w + bv);
    *(float4*)&z_e_out[(b * 64 + d0 + i) * 64 + s0] = r4;
  }
}

// ---------- VQ argmin + loss accum + dproj fused; grid 2048, block 64 --------
__global__ __launch_bounds__(64) void k_vqdproj(const float* __restrict__ z_e,
                                                const float* __restrict__ cbT,
                                                const float* __restrict__ cb,
                                                const float* __restrict__ wdT,
                                                const float* __restrict__ db,
                                                float* __restrict__ idx_f,
                                                float* __restrict__ Yr,
                                                float* __restrict__ loss_acc) {
  __shared__ float zs[64];
  int n = blockIdx.x, lane = threadIdx.x;
  int b = n >> 6, pi = n & 63;
  zs[lane] = z_e[(b * 64 + lane) * 64 + pi];
  __syncthreads();
  double best = 1e300;
  int bi = 0;
#pragma unroll 2
  for (int j = 0; j < 8; j++) {
    int k = j * 64 + lane;
    double acc = 0.0;
#pragma unroll 8
    for (int d = 0; d < 64; d++) {
      float c = cbT[d * 512 + k];
      double diff = (double)zs[d] - (double)c;
      acc = fma(diff, diff, acc);
    }
    if (acc < best) { best = acc; bi = k; }
  }
  for (int m = 1; m < 64; m <<= 1) {
    double ob = __shfl_xor(best, m, 64);
    int oi = __shfl_xor(bi, m, 64);
    if (ob < best || (ob == best && oi < bi)) { best = ob; bi = oi; }
  }
  float zq_l = cb[bi * 64 + lane];
  float e = zq_l - zs[lane];
  float sq = e * e;
  for (int m = 1; m < 64; m <<= 1) sq += __shfl_xor(sq, m, 64);
  if (lane == 0) {
    idx_f[n] = (float)bi;
    atomicAdd(loss_acc, sq);
  }
  __syncthreads();
  zs[lane] = zq_l;  // zq into LDS
  __syncthreads();
  float a0 = db[lane], a1 = db[lane + 64];
#pragma unroll 4
  for (int d = 0; d < 64; d++) {
    float z = zs[d];
    a0 = fmaf(wdT[d * 128 + lane], z, a0);
    a1 = fmaf(wdT[d * 128 + lane + 64], z, a1);
  }
  Yr[(b * 128 + lane) * 64 + pi] = fmaxf(a0, 0.f);
  Yr[(b * 128 + lane + 64) * 64 + pi] = fmaxf(a1, 0.f);
}

// ---------- dec: G[pq][n][co] = sum_ci A[pq][ci][co] * Yshift[ci][n] ----------
__global__ __launch_bounds__(256) void k_dec(const float* __restrict__ Yr,
                                             const float* __restrict__ A,
                                             float* __restrict__ G) {
  __shared__ float Bs[16][256];
  int bx = blockIdx.x;
  int co_t = bx & 3, n_t = bx >> 2;
  int pq = blockIdx.y;
  int py = pq / 5, px = pq - py * 5;
  int dy = (py == 0) ? -1 : ((py == 4) ? 1 : 0);
  int dx = (px == 0) ? -1 : ((px == 4) ? 1 : 0);
  int tid = threadIdx.x;
  int wv = __builtin_amdgcn_readfirstlane(tid >> 6);
  int l = tid & 63;
  int coB = co_t * 32 + wv * 8;
  int nB = n_t * 256;

  float4 acc[8];
#pragma unroll
  for (int q = 0; q < 8; q++) acc[q] = make_float4(0.f, 0.f, 0.f, 0.f);

  for (int ci0 = 0; ci0 < 128; ci0 += 16) {
    __syncthreads();
    for (int idx = tid; idx < 4096; idx += 256) {
      int nn = idx & 255, kk = idx >> 8;
      int n = nB + nn;
      int bb = n >> 6, s = n & 63;
      int sy = (s >> 3) + dy, sx = (s & 7) + dx;
      float v = 0.f;
      if ((unsigned)sy < 8u && (unsigned)sx < 8u)
        v = Yr[(bb * 128 + ci0 + kk) * 64 + sy * 8 + sx];
      Bs[kk][nn] = v;
    }
    __syncthreads();
    for (int kk = 0; kk < 16; kk++) {
      float4 bb4 = *(float4*)&Bs[kk][l * 4];
      const float* ar = A + pq * 16384 + (ci0 + kk) * 128 + coB;
#pragma unroll
      for (int q = 0; q < 8; q++) {
        float av = ar[q];
        acc[q].x = fmaf(av, bb4.x, acc[q].x);
        acc[q].y = fmaf(av, bb4.y, acc[q].y);
        acc[q].z = fmaf(av, bb4.z, acc[q].z);
        acc[q].w = fmaf(av, bb4.w, acc[q].w);
      }
    }
  }
  int nbase = nB + l * 4;
#pragma unroll
  for (int j = 0; j < 4; j++) {
    float* gp = &G[(pq * 2048 + nbase + j) * 128 + coB];
    const float* af = (const float*)acc;
    float4 g0 = make_float4(af[0 * 4 + j], af[1 * 4 + j], af[2 * 4 + j], af[3 * 4 + j]);
    float4 g1 = make_float4(af[4 * 4 + j], af[5 * 4 + j], af[6 * 4 + j], af[7 * 4 + j]);
    *(float4*)gp = g0;
    *(float4*)(gp + 4) = g1;
  }
}

// ---------- out: combine G per class, bias+relu, 1x1 conv to 3ch, splat ------
__global__ __launch_bounds__(256) void k_out(const float* __restrict__ G,
                                             const float* __restrict__ bc1,
                                             const float* __restrict__ w3,
                                             const float* __restrict__ b3,
                                             float* __restrict__ xhat,
                                             const float* __restrict__ loss_acc,
                                             float* __restrict__ out_loss) {
  __shared__ float Tb[9][128];
  __shared__ float part[9][3][8];
  __shared__ float vals[9][3];
  int bj = blockIdx.x, bi = blockIdx.y, b = blockIdx.z;
  int s = bi * 8 + bj;
  int n = b * 64 + s;
  int tid = threadIdx.x;
  if (bj == 0 && bi == 0 && b == 0 && tid == 0)
    out_loss[0] = loss_acc[0] * 1.25f / 131072.0f;
  int co = tid & 127, h = tid >> 7;
  const int rset[3][2] = {{0, 1}, {2, 2}, {3, 4}};
  const int rcnt[3] = {2, 1, 2};
  for (int cls = h; cls < 9; cls += 2) {
    int r = cls / 3, c = cls - r * 3;
    float sum = bc1[co];
    for (int iy = 0; iy < rcnt[r]; iy++) {
      int py = rset[r][iy];
      for (int ix = 0; ix < rcnt[c]; ix++) {
        int px = rset[c][ix];
        sum += G[((py * 5 + px) * 2048 + n) * 128 + co];
      }
    }
    Tb[cls][co] = fmaxf(sum, 0.f);
  }
  __syncthreads();
  if (tid < 216) {
    int cls = tid / 24, rem = tid - cls * 24;
    int cc = rem >> 3, seg = rem & 7;
    float ss = 0.f;
#pragma unroll
    for (int d = 0; d < 16; d++) ss = fmaf(w3[cc * 128 + seg * 16 + d], Tb[cls][seg * 16 + d], ss);
    part[cls][cc][seg] = ss;
  }
  __syncthreads();
  if (tid < 27) {
    int cls = tid / 3, cc = tid - cls * 3;
    float ss = b3[cc];
#pragma unroll
    for (int seg = 0; seg < 8; seg++) ss += part[cls][cc][seg];
    vals[cls][cc] = ss;
  }
  __syncthreads();
  for (int i = tid; i < 768; i += 256) {
    int cc = i >> 8, p = i & 255;
    int ry = p >> 4, rx = p & 15;
    int rcls = (ry == 0) ? 0 : ((ry == 15) ? 2 : 1);
    int ccls = (rx == 0) ? 0 : ((rx == 15) ? 2 : 1);
    xhat[((b * 3 + cc) * 128 + bi * 16 + ry) * 128 + bj * 16 + rx] =
        vals[rcls * 3 + ccls][cc];
  }
}

extern "C" void kernel_launch(void* const* d_in, const int* in_sizes, int n_in,
                              void* d_out, int out_size, void* d_ws, size_t ws_size,
                              hipStream_t stream) {
  const float* x   = (const float*)d_in[0];
  const float* w1  = (const float*)d_in[1];
  const float* b1  = (const float*)d_in[2];
  const float* w2  = (const float*)d_in[3];
  const float* b2  = (const float*)d_in[4];
  const float* wp  = (const float*)d_in[5];
  const float* pb  = (const float*)d_in[6];
  const float* cb  = (const float*)d_in[7];
  const float* wd  = (const float*)d_in[8];
  const float* db  = (const float*)d_in[9];
  const float* wc1 = (const float*)d_in[10];
  const float* bc1 = (const float*)d_in[11];
  const float* wc2 = (const float*)d_in[12];
  const float* bc2 = (const float*)d_in[13];
  float* out = (float*)d_out;
  float* ws  = (float*)d_ws;

  // workspace (floats):
  _Float16* h1h = (_Float16*)(ws);             // 8388640 fl
  _Float16* h1l = (_Float16*)(ws + 8388640);   // 8388640 fl
  float* h2     = ws + 16777280;               // 4194304
  _Float16* Wh  = (_Float16*)(ws + 20971584);  // 73728 fl
  _Float16* Wl  = (_Float16*)(ws + 21045312);  // 73728 fl
  float* w1t    = ws + 21119040;               // 3456
  float* wpT    = ws + 21122496;               // 8192
  float* wdT    = ws + 21130688;               // 8192
  float* cbT    = ws + 21138880;               // 32768
  float* A      = ws + 21171648;               // 409600 -> end 21581248
  // overlays inside dead h1h/h1l region (valid after conv2):
  float* G       = ws;                         // 6553600
  float* Yr      = ws + 6553600;               // 262144
  float* lossacc = ws + 6817792;               // 1

  float* o_xhat = out;
  float* o_idx  = out + 1572864;
  float* o_loss = out + 1574912;
  float* o_ze   = out + 1574913;

  k_prep<<<dim3(910), 256, 0, stream>>>(w2, w1, wp, wd, wc1, cb,
                                        w1t, wpT, wdT, cbT, A, Wh, Wl, h1h, h1l);
  k_conv1<<<dim3(4, 16, 32), 256, 0, stream>>>(x, w1t, b1, h1h, h1l);
  k_conv2<<<dim3(1024), 256, 0, stream>>>(h1h, h1l, Wh, Wl, b2, h2);
  k_poolproj<<<dim3(32), 256, 0, stream>>>(h2, wpT, pb, o_ze, lossacc);
  k_vqdproj<<<dim3(2048), 64, 0, stream>>>(o_ze, cbT, cb, wdT, db, o_idx, Yr, lossacc);
  k_dec<<<dim3(32, 25), 256, 0, stream>>>(Yr, A, G);
  k_out<<<dim3(8, 8, 32), 256, 0, stream>>>(G, bc1, wc2, bc2, o_xhat, lossacc, o_loss);
}

// Round 7
// 308.774 us; speedup vs baseline: 1.4875x; 1.1764x over previous
//
#include <hip/hip_runtime.h>
#include <math.h>

// ---------------------------------------------------------------------------
// VQVAE forward. v7: conv2 deeper ILP (unroll 2, VGPR cap), decoder GEMM
// moved to f16-split MFMA (Ah/Al x Yh/Yl), vqdproj 4-acc f64 distances,
// poolproj on 64 blocks. Layouts as v6 (group-8 NHWC h1 planes).
// ---------------------------------------------------------------------------

typedef _Float16 f16x8 __attribute__((ext_vector_type(8)));
typedef float f32x4 __attribute__((ext_vector_type(4)));

#define H1N 16777216  // elements per h1 plane; zero tail after
#define YTAIL (2048 * 128)  // zero page in Yh/Yl for OOB shifts

// ---------- prep: A-agg + f16 split (bx<128), transposes, W split, tails ----
__global__ __launch_bounds__(256) void k_prep(const float* __restrict__ w2,
                                              const float* __restrict__ w1,
                                              const float* __restrict__ wp,
                                              const float* __restrict__ wd,
                                              const float* __restrict__ wd1,
                                              const float* __restrict__ cb,
                                              float* __restrict__ w1t,
                                              float* __restrict__ wpT,
                                              float* __restrict__ wdT,
                                              float* __restrict__ cbT,
                                              _Float16* __restrict__ Ah,
                                              _Float16* __restrict__ Al,
                                              _Float16* __restrict__ Wh,
                                              _Float16* __restrict__ Wl,
                                              _Float16* __restrict__ h1h,
                                              _Float16* __restrict__ h1l) {
  int bx = blockIdx.x, tid = threadIdx.x;
  if (bx < 128) {
    __shared__ float wrow[1152];
    int co = bx;
    for (int i = tid; i < 1152; i += 256) wrow[i] = wd1[co * 1152 + i];
    __syncthreads();
    if (tid < 128) {
      int ci = tid;
      float w[9];
#pragma unroll
      for (int t = 0; t < 9; t++) w[t] = wrow[ci * 9 + t];
      float rx[3][5];
#pragma unroll
      for (int ky = 0; ky < 3; ky++) {
        float a0 = w[ky * 3 + 0], a1 = w[ky * 3 + 1], a2 = w[ky * 3 + 2];
        rx[ky][0] = a0; rx[ky][1] = a1 + a2; rx[ky][2] = a0 + a1 + a2;
        rx[ky][3] = a0 + a1; rx[ky][4] = a2;
      }
#pragma unroll
      for (int px = 0; px < 5; px++) {
        float s0 = rx[0][px], s1 = rx[1][px], s2 = rx[2][px];
        float ry[5];
        ry[0] = s0; ry[1] = s1 + s2; ry[2] = s0 + s1 + s2; ry[3] = s0 + s1; ry[4] = s2;
#pragma unroll
        for (int py = 0; py < 5; py++) {
          int pq = py * 5 + px;
          float v = ry[py];
          _Float16 h = (_Float16)v;
          int o = (pq * 128 + co) * 128 + ci;  // Ah[pq][co][ci]
          Ah[o] = h;
          Al[o] = (_Float16)(v - (float)h);
        }
      }
    }
    return;
  }
  int i = (bx - 128) * 256 + tid;
  if (i < 3456) {                      // w1t[t][co] = w1[co][t]
    int co = i / 27, t = i - co * 27;
    w1t[t * 128 + co] = w1[i];
  } else if (i < 11648) {              // wpT[k][d] = wp[d][k]
    int j = i - 3456;
    int d = j >> 7, k = j & 127;
    wpT[k * 64 + d] = wp[j];
  } else if (i < 19840) {              // wdT[d][co] = wd[co][d]
    int j = i - 11648;
    int co = j >> 6, d = j & 63;
    wdT[d * 128 + co] = wd[j];
  } else if (i < 52608) {              // cbT[d][k] = cb[k][d]
    int j = i - 19840;
    int k = j >> 6, d = j & 63;
    cbT[d * 512 + k] = cb[j];
  } else if (i < 200064) {             // W f16-split: Wh/Wl[tap][co][ci]
    int j = i - 52608;                 // w2[co][ci][tap]
    int co = j / 1152, r = j - co * 1152;
    int ci = r / 9, tap = r - ci * 9;
    float x = w2[j];
    _Float16 h = (_Float16)x;
    int o = (tap * 128 + co) * 128 + ci;
    Wh[o] = h;
    Wl[o] = (_Float16)(x - (float)h);
  } else if (i < 200128) {             // zero tails for h1 planes
    h1h[H1N + (i - 200064)] = (_Float16)0.f;
  } else if (i < 200192) {
    h1l[H1N + (i - 200128)] = (_Float16)0.f;
  }
}

// ---------- conv1: (32,3,128,128) -> h1 f16-split [g][b][oh][ow][8ci] -------
__global__ __launch_bounds__(256) void k_conv1(const float* __restrict__ x,
                                               const float* __restrict__ w1t,
                                               const float* __restrict__ b1,
                                               _Float16* __restrict__ h1h,
                                               _Float16* __restrict__ h1l) {
  __shared__ float E[3][9][68];
  __shared__ float O[3][9][68];
  int co_t = blockIdx.x, oh_t = blockIdx.y, b = blockIdx.z;
  int oh0 = oh_t * 4;
  int tid = threadIdx.x;
  int wv = __builtin_amdgcn_readfirstlane(tid >> 6);
  int l = tid & 63;
  int coB = co_t * 32 + wv * 8;

  for (int idx = tid; idx < 1728; idx += 256) {
    int p = idx & 63, r = idx >> 6;
    int ci = r / 9, lr = r - ci * 9;
    int ih = 2 * oh0 - 1 + lr;
    float2 v = make_float2(0.f, 0.f);
    if ((unsigned)ih < 128u)
      v = *(const float2*)&x[((b * 3 + ci) * 128 + ih) * 128 + 2 * p];
    E[ci][lr][p] = v.x;
    O[ci][lr][p + 1] = v.y;
  }
  if (tid < 27) {
    int ci = tid / 9, lr = tid - ci * 9;
    O[ci][lr][0] = 0.f;
  }
  __syncthreads();

  int ohl = l >> 4, ow0 = (l & 15) * 4;
  int oh = oh0 + ohl;
  float4 acc[8];
#pragma unroll
  for (int q = 0; q < 8; q++) {
    float bv = b1[coB + q];
    acc[q] = make_float4(bv, bv, bv, bv);
  }
#pragma unroll
  for (int ci = 0; ci < 3; ci++) {
#pragma unroll
    for (int ky = 0; ky < 3; ky++) {
      int lr = 2 * ohl + ky;
      float4 ev = *(float4*)&E[ci][lr][ow0];
      float4 od = *(float4*)&O[ci][lr][ow0];
      float o4 = O[ci][lr][ow0 + 4];
      const float* wr = w1t + (ci * 9 + ky * 3) * 128 + coB;
#pragma unroll
      for (int q = 0; q < 8; q++) {
        float wa = wr[q], wb = wr[128 + q], wc = wr[256 + q];
        acc[q].x = fmaf(wa, od.x, acc[q].x);
        acc[q].x = fmaf(wb, ev.x, acc[q].x);
        acc[q].x = fmaf(wc, od.y, acc[q].x);
        acc[q].y = fmaf(wa, od.y, acc[q].y);
        acc[q].y = fmaf(wb, ev.y, acc[q].y);
        acc[q].y = fmaf(wc, od.z, acc[q].y);
        acc[q].z = fmaf(wa, od.z, acc[q].z);
        acc[q].z = fmaf(wb, ev.z, acc[q].z);
        acc[q].z = fmaf(wc, od.w, acc[q].z);
        acc[q].w = fmaf(wa, od.w, acc[q].w);
        acc[q].w = fmaf(wb, ev.w, acc[q].w);
        acc[q].w = fmaf(wc, o4,   acc[q].w);
      }
    }
  }
  int g = coB >> 3;
  int pbase = ((g * 32 + b) * 64 + oh) * 64;
#pragma unroll
  for (int oi = 0; oi < 4; oi++) {
    f16x8 hv, lv;
#pragma unroll
    for (int q = 0; q < 8; q++) {
      float v = fmaxf(((const float*)&acc[q])[oi], 0.f);
      _Float16 h = (_Float16)v;
      float rem = v - (float)h;
      hv[q] = h;
      lv[q] = (_Float16)rem;
    }
    int base = (pbase + ow0 + oi) * 8;
    *(f16x8*)&h1h[base] = hv;
    *(f16x8*)&h1l[base] = lv;
  }
}

// ---------- conv2: f16-split MFMA, 9 shifted GEMMs, no LDS ----------
// 4096 waves: wave tile = 32co x (1oh x 32ow). grid 1024 x 256thr.
__global__ __launch_bounds__(256, 4) void k_conv2(const _Float16* __restrict__ h1h,
                                                  const _Float16* __restrict__ h1l,
                                                  const _Float16* __restrict__ Wh,
                                                  const _Float16* __restrict__ Wl,
                                                  const float* __restrict__ b2,
                                                  float* __restrict__ h2) {
  int wid = blockIdx.x * 4 + (threadIdx.x >> 6);
  int l = threadIdx.x & 63;
  int ln = l & 15, quad = l >> 4;
  int coW = (wid & 3) * 32;
  int nT = wid >> 2;                  // [0,1024)
  int b = nT >> 5, oh = nT & 31;
  int kq = quad * 8;
  f32x4 acc[2][2] = {};               // [cs][s]

  for (int ky = 0; ky < 3; ky++) {
    int ih = 2 * oh - 1 + ky;         // -1 only when oh==0, ky==0
#pragma unroll 2
    for (int ci0 = 0; ci0 < 128; ci0 += 32) {
      int g8 = ((ci0 >> 3) + quad) * 32 + b;
#pragma unroll
      for (int kx = 0; kx < 3; kx++) {
        int tap = ky * 3 + kx;
        const int wbase = (tap * 128 + coW + ln) * 128 + ci0 + kq;
        f16x8 Ah0 = *(const f16x8*)&Wh[wbase];
        f16x8 Al0 = *(const f16x8*)&Wl[wbase];
        f16x8 Ah1 = *(const f16x8*)&Wh[wbase + 2048];  // +16 co
        f16x8 Al1 = *(const f16x8*)&Wl[wbase + 2048];
        f16x8 Bh[2], Bl[2];
#pragma unroll
        for (int s = 0; s < 2; s++) {
          int iw = 2 * (s * 16 + ln) - 1 + kx;
          int idx = ((g8 * 64 + ih) * 64 + iw) * 8;
          bool ok = (ih >= 0) && (iw >= 0);
          idx = ok ? idx : H1N;       // zero tail
          Bh[s] = *(const f16x8*)&h1h[idx];
          Bl[s] = *(const f16x8*)&h1l[idx];
        }
#pragma unroll
        for (int cs = 0; cs < 2; cs++) {
          f16x8 ah = cs ? Ah1 : Ah0;
          f16x8 al = cs ? Al1 : Al0;
#pragma unroll
          for (int s = 0; s < 2; s++) {
            acc[cs][s] = __builtin_amdgcn_mfma_f32_16x16x32_f16(al, Bh[s], acc[cs][s], 0, 0, 0);
            acc[cs][s] = __builtin_amdgcn_mfma_f32_16x16x32_f16(ah, Bl[s], acc[cs][s], 0, 0, 0);
            acc[cs][s] = __builtin_amdgcn_mfma_f32_16x16x32_f16(ah, Bh[s], acc[cs][s], 0, 0, 0);
          }
        }
      }
    }
  }
#pragma unroll
  for (int cs = 0; cs < 2; cs++)
#pragma unroll
    for (int s = 0; s < 2; s++) {
      int ow = s * 16 + ln;
#pragma unroll
      for (int r = 0; r < 4; r++) {
        int co = coW + cs * 16 + quad * 4 + r;
        h2[((b * 128 + co) * 32 + oh) * 32 + ow] = fmaxf(acc[cs][s][r] + b2[co], 0.f);
      }
    }
}

// ---------- pool(4x4 mean) + proj(1x1,128->64); grid 64 (b, site-half) ------
__global__ __launch_bounds__(256) void k_poolproj(const float* __restrict__ h2,
                                                  const float* __restrict__ wpT,
                                                  const float* __restrict__ pb,
                                                  float* __restrict__ z_e_out,
                                                  float* __restrict__ lossacc) {
  __shared__ float hp[128][32];
  __shared__ float Ws[128][64];
  int bx = blockIdx.x, tid = threadIdx.x;
  int b = bx >> 1, half = bx & 1;
  if (bx == 0 && tid == 0) lossacc[0] = 0.f;
  for (int i = tid; i < 8192; i += 256) Ws[i >> 6][i & 63] = wpT[i];
  for (int i = tid; i < 4096; i += 256) {
    int ci = i >> 5, pl = i & 31;
    int pi = half * 32 + pl;
    int bi = pi >> 3, bj = pi & 7;
    const float* src = &h2[((b * 128 + ci) * 32 + bi * 4) * 32 + bj * 4];
    float4 r0 = *(const float4*)src;
    float4 r1 = *(const float4*)(src + 32);
    float4 r2 = *(const float4*)(src + 64);
    float4 r3 = *(const float4*)(src + 96);
    float s = r0.x + r0.y + r0.z + r0.w + r1.x + r1.y + r1.z + r1.w +
              r2.x + r2.y + r2.z + r2.w + r3.x + r3.y + r3.z + r3.w;
    hp[ci][pl] = s * 0.0625f;
  }
  __syncthreads();
  int ty = tid >> 3, tx = tid & 7;      // ty: 32 d-pairs, tx: 8 site-quads
  int d0 = ty * 2, s0 = tx * 4;
  float4 acc[2] = {make_float4(0.f, 0.f, 0.f, 0.f), make_float4(0.f, 0.f, 0.f, 0.f)};
  for (int k = 0; k < 128; k++) {
    float a0 = Ws[k][d0], a1 = Ws[k][d0 + 1];
    float4 h = *(float4*)&hp[k][s0];
    acc[0].x = fmaf(a0, h.x, acc[0].x); acc[0].y = fmaf(a0, h.y, acc[0].y);
    acc[0].z = fmaf(a0, h.z, acc[0].z); acc[0].w = fmaf(a0, h.w, acc[0].w);
    acc[1].x = fmaf(a1, h.x, acc[1].x); acc[1].y = fmaf(a1, h.y, acc[1].y);
    acc[1].z = fmaf(a1, h.z, acc[1].z); acc[1].w = fmaf(a1, h.w, acc[1].w);
  }
#pragma unroll
  for (int i = 0; i < 2; i++) {
    float bv = pb[d0 + i];
    float4 r4 = make_float4(acc[i].x + bv, acc[i].y + bv, acc[i].z + bv, acc[i].w + bv);
    *(float4*)&z_e_out[(b * 64 + d0 + i) * 64 + half * 32 + s0] = r4;
  }
}

// ---------- VQ argmin + loss + dproj -> Yh/Yl f16 planes; grid 2048 ----------
__global__ __launch_bounds__(64) void k_vqdproj(const float* __restrict__ z_e,
                                                const float* __restrict__ cbT,
                                                const float* __restrict__ cb,
                                                const float* __restrict__ wdT,
                                                const float* __restrict__ db,
                                                float* __restrict__ idx_f,
                                                _Float16* __restrict__ Yh,
                                                _Float16* __restrict__ Yl,
                                                float* __restrict__ loss_acc) {
  __shared__ float zs[64];
  int n = blockIdx.x, lane = threadIdx.x;
  int b = n >> 6, pi = n & 63;
  zs[lane] = z_e[(b * 64 + lane) * 64 + pi];
  if (n == 0) {  // zero tail page for shifted reads in k_dec
    Yh[YTAIL + lane] = (_Float16)0.f;
    Yh[YTAIL + 64 + lane] = (_Float16)0.f;
    Yl[YTAIL + lane] = (_Float16)0.f;
    Yl[YTAIL + 64 + lane] = (_Float16)0.f;
  }
  __syncthreads();
  double best = 1e300;
  int bi = 0;
#pragma unroll 2
  for (int j = 0; j < 8; j++) {
    int k = j * 64 + lane;
    double a0 = 0.0, a1 = 0.0, a2 = 0.0, a3 = 0.0;
#pragma unroll 4
    for (int d = 0; d < 64; d += 4) {
      double f0 = (double)zs[d] - (double)cbT[d * 512 + k];
      double f1 = (double)zs[d + 1] - (double)cbT[(d + 1) * 512 + k];
      double f2 = (double)zs[d + 2] - (double)cbT[(d + 2) * 512 + k];
      double f3 = (double)zs[d + 3] - (double)cbT[(d + 3) * 512 + k];
      a0 = fma(f0, f0, a0);
      a1 = fma(f1, f1, a1);
      a2 = fma(f2, f2, a2);
      a3 = fma(f3, f3, a3);
    }
    double acc = (a0 + a1) + (a2 + a3);
    if (acc < best) { best = acc; bi = k; }
  }
  for (int m = 1; m < 64; m <<= 1) {
    double ob = __shfl_xor(best, m, 64);
    int oi = __shfl_xor(bi, m, 64);
    if (ob < best || (ob == best && oi < bi)) { best = ob; bi = oi; }
  }
  float zq_l = cb[bi * 64 + lane];
  float e = zq_l - zs[lane];
  float sq = e * e;
  for (int m = 1; m < 64; m <<= 1) sq += __shfl_xor(sq, m, 64);
  if (lane == 0) {
    idx_f[n] = (float)bi;
    atomicAdd(loss_acc, sq);
  }
  __syncthreads();
  zs[lane] = zq_l;
  __syncthreads();
  float a0 = db[lane], a1 = db[lane + 64];
#pragma unroll 4
  for (int d = 0; d < 64; d++) {
    float z = zs[d];
    a0 = fmaf(wdT[d * 128 + lane], z, a0);
    a1 = fmaf(wdT[d * 128 + lane + 64], z, a1);
  }
  float y0 = fmaxf(a0, 0.f), y1 = fmaxf(a1, 0.f);
  _Float16 h0 = (_Float16)y0, h1v = (_Float16)y1;
  Yh[n * 128 + lane] = h0;
  Yh[n * 128 + lane + 64] = h1v;
  Yl[n * 128 + lane] = (_Float16)(y0 - (float)h0);
  Yl[n * 128 + lane + 64] = (_Float16)(y1 - (float)h1v);
}

// ---------- dec: f16-split MFMA, G[pq][n][co] = A_pq * Yshift ----------
// grid 1600 = 25pq x 64 n_t; block 256 (4 waves = 4 co-tiles).
__global__ __launch_bounds__(256) void k_dec(const _Float16* __restrict__ Yh,
                                             const _Float16* __restrict__ Yl,
                                             const _Float16* __restrict__ Ah,
                                             const _Float16* __restrict__ Al,
                                             float* __restrict__ G) {
  int bxx = blockIdx.x;
  int pq = bxx >> 6, n_t = bxx & 63;
  int w = threadIdx.x >> 6, l = threadIdx.x & 63;
  int ln = l & 15, quad = l >> 4;
  int coW = w * 32;
  int nB = n_t * 32;
  int py = pq / 5, px = pq - py * 5;
  int dy = (py == 0) ? -1 : ((py == 4) ? 1 : 0);
  int dx = (px == 0) ? -1 : ((px == 4) ? 1 : 0);
  int src[2];
#pragma unroll
  for (int s = 0; s < 2; s++) {
    int n = nB + s * 16 + ln;
    int bb = n >> 6, s6 = n & 63;
    int sy = (s6 >> 3) + dy, sx = (s6 & 7) + dx;
    bool ok = ((unsigned)sy < 8u) && ((unsigned)sx < 8u);
    src[s] = ok ? ((bb * 64 + sy * 8 + sx) * 128) : YTAIL;
  }
  int kq = quad * 8;
  f32x4 acc[2][2] = {};
#pragma unroll 2
  for (int ci0 = 0; ci0 < 128; ci0 += 32) {
    const int wbase = (pq * 128 + coW + ln) * 128 + ci0 + kq;
    f16x8 Ah0 = *(const f16x8*)&Ah[wbase];
    f16x8 Al0 = *(const f16x8*)&Al[wbase];
    f16x8 Ah1 = *(const f16x8*)&Ah[wbase + 2048];
    f16x8 Al1 = *(const f16x8*)&Al[wbase + 2048];
    f16x8 Bh[2], Bl[2];
#pragma unroll
    for (int s = 0; s < 2; s++) {
      Bh[s] = *(const f16x8*)&Yh[src[s] + ci0 + kq];
      Bl[s] = *(const f16x8*)&Yl[src[s] + ci0 + kq];
    }
#pragma unroll
    for (int cs = 0; cs < 2; cs++) {
      f16x8 ah = cs ? Ah1 : Ah0;
      f16x8 al = cs ? Al1 : Al0;
#pragma unroll
      for (int s = 0; s < 2; s++) {
        acc[cs][s] = __builtin_amdgcn_mfma_f32_16x16x32_f16(al, Bh[s], acc[cs][s], 0, 0, 0);
        acc[cs][s] = __builtin_amdgcn_mfma_f32_16x16x32_f16(ah, Bl[s], acc[cs][s], 0, 0, 0);
        acc[cs][s] = __builtin_amdgcn_mfma_f32_16x16x32_f16(ah, Bh[s], acc[cs][s], 0, 0, 0);
      }
    }
  }
#pragma unroll
  for (int cs = 0; cs < 2; cs++)
#pragma unroll
    for (int s = 0; s < 2; s++) {
      int site = nB + s * 16 + ln;
      float4 g = make_float4(acc[cs][s][0], acc[cs][s][1], acc[cs][s][2], acc[cs][s][3]);
      *(float4*)&G[(pq * 2048 + site) * 128 + coW + cs * 16 + quad * 4] = g;
    }
}

// ---------- out: combine G per class, bias+relu, 1x1 conv to 3ch, splat ------
__global__ __launch_bounds__(256) void k_out(const float* __restrict__ G,
                                             const float* __restrict__ bc1,
                                             const float* __restrict__ w3,
                                             const float* __restrict__ b3,
                                             float* __restrict__ xhat,
                                             const float* __restrict__ loss_acc,
                                             float* __restrict__ out_loss) {
  __shared__ float Tb[9][128];
  __shared__ float part[9][3][8];
  __shared__ float vals[9][3];
  int bj = blockIdx.x, bi = blockIdx.y, b = blockIdx.z;
  int s = bi * 8 + bj;
  int n = b * 64 + s;
  int tid = threadIdx.x;
  if (bj == 0 && bi == 0 && b == 0 && tid == 0)
    out_loss[0] = loss_acc[0] * 1.25f / 131072.0f;
  int co = tid & 127, h = tid >> 7;
  const int rset[3][2] = {{0, 1}, {2, 2}, {3, 4}};
  const int rcnt[3] = {2, 1, 2};
  for (int cls = h; cls < 9; cls += 2) {
    int r = cls / 3, c = cls - r * 3;
    float sum = bc1[co];
    for (int iy = 0; iy < rcnt[r]; iy++) {
      int py = rset[r][iy];
      for (int ix = 0; ix < rcnt[c]; ix++) {
        int px = rset[c][ix];
        sum += G[((py * 5 + px) * 2048 + n) * 128 + co];
      }
    }
    Tb[cls][co] = fmaxf(sum, 0.f);
  }
  __syncthreads();
  if (tid < 216) {
    int cls = tid / 24, rem = tid - cls * 24;
    int cc = rem >> 3, seg = rem & 7;
    float ss = 0.f;
#pragma unroll
    for (int d = 0; d < 16; d++) ss = fmaf(w3[cc * 128 + seg * 16 + d], Tb[cls][seg * 16 + d], ss);
    part[cls][cc][seg] = ss;
  }
  __syncthreads();
  if (tid < 27) {
    int cls = tid / 3, cc = tid - cls * 3;
    float ss = b3[cc];
#pragma unroll
    for (int seg = 0; seg < 8; seg++) ss += part[cls][cc][seg];
    vals[cls][cc] = ss;
  }
  __syncthreads();
  for (int i = tid; i < 768; i += 256) {
    int cc = i >> 8, p = i & 255;
    int ry = p >> 4, rx = p & 15;
    int rcls = (ry == 0) ? 0 : ((ry == 15) ? 2 : 1);
    int ccls = (rx == 0) ? 0 : ((rx == 15) ? 2 : 1);
    xhat[((b * 3 + cc) * 128 + bi * 16 + ry) * 128 + bj * 16 + rx] =
        vals[rcls * 3 + ccls][cc];
  }
}

extern "C" void kernel_launch(void* const* d_in, const int* in_sizes, int n_in,
                              void* d_out, int out_size, void* d_ws, size_t ws_size,
                              hipStream_t stream) {
  const float* x   = (const float*)d_in[0];
  const float* w1  = (const float*)d_in[1];
  const float* b1  = (const float*)d_in[2];
  const float* w2  = (const float*)d_in[3];
  const float* b2  = (const float*)d_in[4];
  const float* wp  = (const float*)d_in[5];
  const float* pb  = (const float*)d_in[6];
  const float* cb  = (const float*)d_in[7];
  const float* wd  = (const float*)d_in[8];
  const float* db  = (const float*)d_in[9];
  const float* wc1 = (const float*)d_in[10];
  const float* bc1 = (const float*)d_in[11];
  const float* wc2 = (const float*)d_in[12];
  const float* bc2 = (const float*)d_in[13];
  float* out = (float*)d_out;
  float* ws  = (float*)d_ws;

  // workspace (float offsets):
  _Float16* h1h = (_Float16*)(ws);             // [0, 8388640)
  _Float16* h1l = (_Float16*)(ws + 8388640);   // [8388640, 16777280)
  float* h2     = ws + 16777280;               // 4194304
  _Float16* Wh  = (_Float16*)(ws + 20971584);  // 73728 fl
  _Float16* Wl  = (_Float16*)(ws + 21045312);  // 73728 fl
  float* w1t    = ws + 21119040;               // 3456
  float* wpT    = ws + 21122496;               // 8192
  float* wdT    = ws + 21130688;               // 8192
  float* cbT    = ws + 21138880;               // 32768
  _Float16* Ahd = (_Float16*)(ws + 21171648);  // 204800 fl
  _Float16* Ald = (_Float16*)(ws + 21376448);  // 204800 fl -> end 21581248
  // overlays inside dead h1h/h1l region (valid after conv2):
  float* G       = ws;                         // [0, 6553600)
  _Float16* Yh   = (_Float16*)(ws + 6553600);  // 131136 fl (2049*128 f16)
  _Float16* Yl   = (_Float16*)(ws + 6684736);  // 131136 fl
  float* lossacc = ws + 6815872;               // 1

  float* o_xhat = out;
  float* o_idx  = out + 1572864;
  float* o_loss = out + 1574912;
  float* o_ze   = out + 1574913;

  k_prep<<<dim3(910), 256, 0, stream>>>(w2, w1, wp, wd, wc1, cb,
                                        w1t, wpT, wdT, cbT, Ahd, Ald, Wh, Wl, h1h, h1l);
  k_conv1<<<dim3(4, 16, 32), 256, 0, stream>>>(x, w1t, b1, h1h, h1l);
  k_conv2<<<dim3(1024), 256, 0, stream>>>(h1h, h1l, Wh, Wl, b2, h2);
  k_poolproj<<<dim3(64), 256, 0, stream>>>(h2, wpT, pb, o_ze, lossacc);
  k_vqdproj<<<dim3(2048), 64, 0, stream>>>(o_ze, cbT, cb, wdT, db, o_idx, Yh, Yl, lossacc);
  k_dec<<<dim3(1600), 256, 0, stream>>>(Yh, Yl, Ahd, Ald, G);
  k_out<<<dim3(8, 8, 32), 256, 0, stream>>>(G, bc1, wc2, bc2, o_xhat, lossacc, o_loss);
}

// Round 8
// 280.955 us; speedup vs baseline: 1.6347x; 1.0990x over previous
//
#include <hip/hip_runtime.h>
#include <math.h>

// ---------------------------------------------------------------------------
// VQVAE forward. v8: conv2 restructured — block = 128co x 64px, B staged once
// per (ky,ci0) step into LDS (phase-split, 2-way-free banking), shared by all
// 4 waves; A direct-global (L1-hot across 8 waves/CU). Rest identical to v7.
// ---------------------------------------------------------------------------

typedef _Float16 f16x8 __attribute__((ext_vector_type(8)));
typedef float f32x4 __attribute__((ext_vector_type(4)));

#define H1N 16777216        // elements per h1 plane; zero tail after
#define H1PL 16777280       // f16 offset between h1h and h1l planes
#define YTAIL (2048 * 128)  // zero page in Yh/Yl for OOB shifts

// ---------- prep: A-agg + f16 split (bx<128), transposes, W split, tails ----
__global__ __launch_bounds__(256) void k_prep(const float* __restrict__ w2,
                                              const float* __restrict__ w1,
                                              const float* __restrict__ wp,
                                              const float* __restrict__ wd,
                                              const float* __restrict__ wd1,
                                              const float* __restrict__ cb,
                                              float* __restrict__ w1t,
                                              float* __restrict__ wpT,
                                              float* __restrict__ wdT,
                                              float* __restrict__ cbT,
                                              _Float16* __restrict__ Ah,
                                              _Float16* __restrict__ Al,
                                              _Float16* __restrict__ Wh,
                                              _Float16* __restrict__ Wl,
                                              _Float16* __restrict__ h1h,
                                              _Float16* __restrict__ h1l) {
  int bx = blockIdx.x, tid = threadIdx.x;
  if (bx < 128) {
    __shared__ float wrow[1152];
    int co = bx;
    for (int i = tid; i < 1152; i += 256) wrow[i] = wd1[co * 1152 + i];
    __syncthreads();
    if (tid < 128) {
      int ci = tid;
      float w[9];
#pragma unroll
      for (int t = 0; t < 9; t++) w[t] = wrow[ci * 9 + t];
      float rx[3][5];
#pragma unroll
      for (int ky = 0; ky < 3; ky++) {
        float a0 = w[ky * 3 + 0], a1 = w[ky * 3 + 1], a2 = w[ky * 3 + 2];
        rx[ky][0] = a0; rx[ky][1] = a1 + a2; rx[ky][2] = a0 + a1 + a2;
        rx[ky][3] = a0 + a1; rx[ky][4] = a2;
      }
#pragma unroll
      for (int px = 0; px < 5; px++) {
        float s0 = rx[0][px], s1 = rx[1][px], s2 = rx[2][px];
        float ry[5];
        ry[0] = s0; ry[1] = s1 + s2; ry[2] = s0 + s1 + s2; ry[3] = s0 + s1; ry[4] = s2;
#pragma unroll
        for (int py = 0; py < 5; py++) {
          int pq = py * 5 + px;
          float v = ry[py];
          _Float16 h = (_Float16)v;
          int o = (pq * 128 + co) * 128 + ci;  // Ah[pq][co][ci]
          Ah[o] = h;
          Al[o] = (_Float16)(v - (float)h);
        }
      }
    }
    return;
  }
  int i = (bx - 128) * 256 + tid;
  if (i < 3456) {                      // w1t[t][co] = w1[co][t]
    int co = i / 27, t = i - co * 27;
    w1t[t * 128 + co] = w1[i];
  } else if (i < 11648) {              // wpT[k][d] = wp[d][k]
    int j = i - 3456;
    int d = j >> 7, k = j & 127;
    wpT[k * 64 + d] = wp[j];
  } else if (i < 19840) {              // wdT[d][co] = wd[co][d]
    int j = i - 11648;
    int co = j >> 6, d = j & 63;
    wdT[d * 128 + co] = wd[j];
  } else if (i < 52608) {              // cbT[d][k] = cb[k][d]
    int j = i - 19840;
    int k = j >> 6, d = j & 63;
    cbT[d * 512 + k] = cb[j];
  } else if (i < 200064) {             // W f16-split: Wh/Wl[tap][co][ci]
    int j = i - 52608;                 // w2[co][ci][tap]
    int co = j / 1152, r = j - co * 1152;
    int ci = r / 9, tap = r - ci * 9;
    float x = w2[j];
    _Float16 h = (_Float16)x;
    int o = (tap * 128 + co) * 128 + ci;
    Wh[o] = h;
    Wl[o] = (_Float16)(x - (float)h);
  } else if (i < 200128) {             // zero tails for h1 planes
    h1h[H1N + (i - 200064)] = (_Float16)0.f;
  } else if (i < 200192) {
    h1l[H1N + (i - 200128)] = (_Float16)0.f;
  }
}

// ---------- conv1: (32,3,128,128) -> h1 f16-split [g][b][oh][ow][8ci] -------
__global__ __launch_bounds__(256) void k_conv1(const float* __restrict__ x,
                                               const float* __restrict__ w1t,
                                               const float* __restrict__ b1,
                                               _Float16* __restrict__ h1h,
                                               _Float16* __restrict__ h1l) {
  __shared__ float E[3][9][68];
  __shared__ float O[3][9][68];
  int co_t = blockIdx.x, oh_t = blockIdx.y, b = blockIdx.z;
  int oh0 = oh_t * 4;
  int tid = threadIdx.x;
  int wv = __builtin_amdgcn_readfirstlane(tid >> 6);
  int l = tid & 63;
  int coB = co_t * 32 + wv * 8;

  for (int idx = tid; idx < 1728; idx += 256) {
    int p = idx & 63, r = idx >> 6;
    int ci = r / 9, lr = r - ci * 9;
    int ih = 2 * oh0 - 1 + lr;
    float2 v = make_float2(0.f, 0.f);
    if ((unsigned)ih < 128u)
      v = *(const float2*)&x[((b * 3 + ci) * 128 + ih) * 128 + 2 * p];
    E[ci][lr][p] = v.x;
    O[ci][lr][p + 1] = v.y;
  }
  if (tid < 27) {
    int ci = tid / 9, lr = tid - ci * 9;
    O[ci][lr][0] = 0.f;
  }
  __syncthreads();

  int ohl = l >> 4, ow0 = (l & 15) * 4;
  int oh = oh0 + ohl;
  float4 acc[8];
#pragma unroll
  for (int q = 0; q < 8; q++) {
    float bv = b1[coB + q];
    acc[q] = make_float4(bv, bv, bv, bv);
  }
#pragma unroll
  for (int ci = 0; ci < 3; ci++) {
#pragma unroll
    for (int ky = 0; ky < 3; ky++) {
      int lr = 2 * ohl + ky;
      float4 ev = *(float4*)&E[ci][lr][ow0];
      float4 od = *(float4*)&O[ci][lr][ow0];
      float o4 = O[ci][lr][ow0 + 4];
      const float* wr = w1t + (ci * 9 + ky * 3) * 128 + coB;
#pragma unroll
      for (int q = 0; q < 8; q++) {
        float wa = wr[q], wb = wr[128 + q], wc = wr[256 + q];
        acc[q].x = fmaf(wa, od.x, acc[q].x);
        acc[q].x = fmaf(wb, ev.x, acc[q].x);
        acc[q].x = fmaf(wc, od.y, acc[q].x);
        acc[q].y = fmaf(wa, od.y, acc[q].y);
        acc[q].y = fmaf(wb, ev.y, acc[q].y);
        acc[q].y = fmaf(wc, od.z, acc[q].y);
        acc[q].z = fmaf(wa, od.z, acc[q].z);
        acc[q].z = fmaf(wb, ev.z, acc[q].z);
        acc[q].z = fmaf(wc, od.w, acc[q].z);
        acc[q].w = fmaf(wa, od.w, acc[q].w);
        acc[q].w = fmaf(wb, ev.w, acc[q].w);
        acc[q].w = fmaf(wc, o4,   acc[q].w);
      }
    }
  }
  int g = coB >> 3;
  int pbase = ((g * 32 + b) * 64 + oh) * 64;
#pragma unroll
  for (int oi = 0; oi < 4; oi++) {
    f16x8 hv, lv;
#pragma unroll
    for (int q = 0; q < 8; q++) {
      float v = fmaxf(((const float*)&acc[q])[oi], 0.f);
      _Float16 h = (_Float16)v;
      float rem = v - (float)h;
      hv[q] = h;
      lv[q] = (_Float16)rem;
    }
    int base = (pbase + ow0 + oi) * 8;
    *(f16x8*)&h1h[base] = hv;
    *(f16x8*)&h1l[base] = lv;
  }
}

// ---------- conv2: f16-split MFMA; block = 128co x 64px, LDS-staged B --------
// grid 512 = (b(32) x ohp(16)); block 256 = 4 waves (wave w: co 32w..32w+31).
// LDS B layout: chunk c = ((g*2+r)*2+pl)*65 + (ph? 33+u : u), 16 B per chunk.
//   ph=0: odd iw = 2u-1 (u=0..32); ph=1: even iw = 2u (u=0..31).
__global__ __launch_bounds__(256) void k_conv2(const _Float16* __restrict__ h1h,
                                               const _Float16* __restrict__ Wh,
                                               const _Float16* __restrict__ Wl,
                                               const float* __restrict__ b2,
                                               float* __restrict__ h2) {
  __shared__ _Float16 Bbuf[8320];  // 1040 chunks x 16 B = 16640 B
  int bx = blockIdx.x;
  int b = bx >> 4, ohp = bx & 15;
  int oh0 = ohp * 2;
  int tid = threadIdx.x;
  int w = tid >> 6, l = tid & 63;
  int ln = l & 15, quad = l >> 4;
  int coW = w * 32;
  int kq = quad * 8;
  f32x4 acc[2][4] = {};  // [cs][s]

  for (int ky = 0; ky < 3; ky++) {
    int ihB = 2 * oh0 - 1 + ky;
    for (int ci0 = 0; ci0 < 128; ci0 += 32) {
      __syncthreads();
      // ---- stage B: rows ihB, ihB+2 for 4 ci-groups, both planes ----
      for (int c = tid; c < 1040; c += 256) {
        int q = c / 65, rem = c - q * 65;
        int ph = rem >= 33;
        int u = ph ? rem - 33 : rem;
        int pl = q & 1, r = (q >> 1) & 1, g = q >> 2;
        int iw = ph ? 2 * u : 2 * u - 1;
        int ih = ihB + 2 * r;
        bool ok = (ih >= 0) && (iw >= 0) && (iw < 64);
        int src = pl * H1PL + (ok ? ((((ci0 >> 3) + g) * 32 + b) * 64 + ih) * 512 + iw * 8
                                  : H1N);
        *(f16x8*)&Bbuf[c * 8] = *(const f16x8*)&h1h[src];
      }
      __syncthreads();
      // ---- compute: 3 kx taps ----
#pragma unroll
      for (int kx = 0; kx < 3; kx++) {
        int tap = ky * 3 + kx;
        const int wbase = (tap * 128 + coW + ln) * 128 + ci0 + kq;
        f16x8 Ah0 = *(const f16x8*)&Wh[wbase];
        f16x8 Al0 = *(const f16x8*)&Wl[wbase];
        f16x8 Ah1 = *(const f16x8*)&Wh[wbase + 2048];  // +16 co
        f16x8 Al1 = *(const f16x8*)&Wl[wbase + 2048];
#pragma unroll
        for (int s = 0; s < 4; s++) {
          int owl = (s & 1) * 16 + ln;
          int base = ((quad * 2 + (s >> 1)) * 2) * 65;
          int uoff = (kx == 1) ? (33 + owl) : (owl + (kx == 2));
          f16x8 Bh = *(const f16x8*)&Bbuf[(base + uoff) * 8];
          f16x8 Bl = *(const f16x8*)&Bbuf[(base + 65 + uoff) * 8];
          acc[0][s] = __builtin_amdgcn_mfma_f32_16x16x32_f16(Al0, Bh, acc[0][s], 0, 0, 0);
          acc[0][s] = __builtin_amdgcn_mfma_f32_16x16x32_f16(Ah0, Bl, acc[0][s], 0, 0, 0);
          acc[0][s] = __builtin_amdgcn_mfma_f32_16x16x32_f16(Ah0, Bh, acc[0][s], 0, 0, 0);
          acc[1][s] = __builtin_amdgcn_mfma_f32_16x16x32_f16(Al1, Bh, acc[1][s], 0, 0, 0);
          acc[1][s] = __builtin_amdgcn_mfma_f32_16x16x32_f16(Ah1, Bl, acc[1][s], 0, 0, 0);
          acc[1][s] = __builtin_amdgcn_mfma_f32_16x16x32_f16(Ah1, Bh, acc[1][s], 0, 0, 0);
        }
      }
    }
  }
  // epilogue: C row = co (quad*4+reg), col = px (lane&15)
#pragma unroll
  for (int cs = 0; cs < 2; cs++)
#pragma unroll
    for (int s = 0; s < 4; s++) {
      int oh = oh0 + (s >> 1);
      int ow = (s & 1) * 16 + ln;
#pragma unroll
      for (int r = 0; r < 4; r++) {
        int co = coW + cs * 16 + quad * 4 + r;
        h2[((b * 128 + co) * 32 + oh) * 32 + ow] = fmaxf(acc[cs][s][r] + b2[co], 0.f);
      }
    }
}

// ---------- pool(4x4 mean) + proj(1x1,128->64); grid 64 (b, site-half) ------
__global__ __launch_bounds__(256) void k_poolproj(const float* __restrict__ h2,
                                                  const float* __restrict__ wpT,
                                                  const float* __restrict__ pb,
                                                  float* __restrict__ z_e_out,
                                                  float* __restrict__ lossacc) {
  __shared__ float hp[128][32];
  __shared__ float Ws[128][64];
  int bx = blockIdx.x, tid = threadIdx.x;
  int b = bx >> 1, half = bx & 1;
  if (bx == 0 && tid == 0) lossacc[0] = 0.f;
  for (int i = tid; i < 8192; i += 256) Ws[i >> 6][i & 63] = wpT[i];
  for (int i = tid; i < 4096; i += 256) {
    int ci = i >> 5, pl = i & 31;
    int pi = half * 32 + pl;
    int bi = pi >> 3, bj = pi & 7;
    const float* src = &h2[((b * 128 + ci) * 32 + bi * 4) * 32 + bj * 4];
    float4 r0 = *(const float4*)src;
    float4 r1 = *(const float4*)(src + 32);
    float4 r2 = *(const float4*)(src + 64);
    float4 r3 = *(const float4*)(src + 96);
    float s = r0.x + r0.y + r0.z + r0.w + r1.x + r1.y + r1.z + r1.w +
              r2.x + r2.y + r2.z + r2.w + r3.x + r3.y + r3.z + r3.w;
    hp[ci][pl] = s * 0.0625f;
  }
  __syncthreads();
  int ty = tid >> 3, tx = tid & 7;
  int d0 = ty * 2, s0 = tx * 4;
  float4 acc[2] = {make_float4(0.f, 0.f, 0.f, 0.f), make_float4(0.f, 0.f, 0.f, 0.f)};
  for (int k = 0; k < 128; k++) {
    float a0 = Ws[k][d0], a1 = Ws[k][d0 + 1];
    float4 h = *(float4*)&hp[k][s0];
    acc[0].x = fmaf(a0, h.x, acc[0].x); acc[0].y = fmaf(a0, h.y, acc[0].y);
    acc[0].z = fmaf(a0, h.z, acc[0].z); acc[0].w = fmaf(a0, h.w, acc[0].w);
    acc[1].x = fmaf(a1, h.x, acc[1].x); acc[1].y = fmaf(a1, h.y, acc[1].y);
    acc[1].z = fmaf(a1, h.z, acc[1].z); acc[1].w = fmaf(a1, h.w, acc[1].w);
  }
#pragma unroll
  for (int i = 0; i < 2; i++) {
    float bv = pb[d0 + i];
    float4 r4 = make_float4(acc[i].x + bv, acc[i].y + bv, acc[i].z + bv, acc[i].w + bv);
    *(float4*)&z_e_out[(b * 64 + d0 + i) * 64 + half * 32 + s0] = r4;
  }
}

// ---------- VQ argmin + loss + dproj -> Yh/Yl f16 planes; grid 2048 ----------
__global__ __launch_bounds__(64) void k_vqdproj(const float* __restrict__ z_e,
                                                const float* __restrict__ cbT,
                                                const float* __restrict__ cb,
                                                const float* __restrict__ wdT,
                                                const float* __restrict__ db,
                                                float* __restrict__ idx_f,
                                                _Float16* __restrict__ Yh,
                                                _Float16* __restrict__ Yl,
                                                float* __restrict__ loss_acc) {
  __shared__ float zs[64];
  int n = blockIdx.x, lane = threadIdx.x;
  int b = n >> 6, pi = n & 63;
  zs[lane] = z_e[(b * 64 + lane) * 64 + pi];
  if (n == 0) {  // zero tail page for shifted reads in k_dec
    Yh[YTAIL + lane] = (_Float16)0.f;
    Yh[YTAIL + 64 + lane] = (_Float16)0.f;
    Yl[YTAIL + lane] = (_Float16)0.f;
    Yl[YTAIL + 64 + lane] = (_Float16)0.f;
  }
  __syncthreads();
  double best = 1e300;
  int bi = 0;
#pragma unroll 2
  for (int j = 0; j < 8; j++) {
    int k = j * 64 + lane;
    double a0 = 0.0, a1 = 0.0, a2 = 0.0, a3 = 0.0;
#pragma unroll 4
    for (int d = 0; d < 64; d += 4) {
      double f0 = (double)zs[d] - (double)cbT[d * 512 + k];
      double f1 = (double)zs[d + 1] - (double)cbT[(d + 1) * 512 + k];
      double f2 = (double)zs[d + 2] - (double)cbT[(d + 2) * 512 + k];
      double f3 = (double)zs[d + 3] - (double)cbT[(d + 3) * 512 + k];
      a0 = fma(f0, f0, a0);
      a1 = fma(f1, f1, a1);
      a2 = fma(f2, f2, a2);
      a3 = fma(f3, f3, a3);
    }
    double acc = (a0 + a1) + (a2 + a3);
    if (acc < best) { best = acc; bi = k; }
  }
  for (int m = 1; m < 64; m <<= 1) {
    double ob = __shfl_xor(best, m, 64);
    int oi = __shfl_xor(bi, m, 64);
    if (ob < best || (ob == best && oi < bi)) { best = ob; bi = oi; }
  }
  float zq_l = cb[bi * 64 + lane];
  float e = zq_l - zs[lane];
  float sq = e * e;
  for (int m = 1; m < 64; m <<= 1) sq += __shfl_xor(sq, m, 64);
  if (lane == 0) {
    idx_f[n] = (float)bi;
    atomicAdd(loss_acc, sq);
  }
  __syncthreads();
  zs[lane] = zq_l;
  __syncthreads();
  float a0 = db[lane], a1 = db[lane + 64];
#pragma unroll 4
  for (int d = 0; d < 64; d++) {
    float z = zs[d];
    a0 = fmaf(wdT[d * 128 + lane], z, a0);
    a1 = fmaf(wdT[d * 128 + lane + 64], z, a1);
  }
  float y0 = fmaxf(a0, 0.f), y1 = fmaxf(a1, 0.f);
  _Float16 h0 = (_Float16)y0, h1v = (_Float16)y1;
  Yh[n * 128 + lane] = h0;
  Yh[n * 128 + lane + 64] = h1v;
  Yl[n * 128 + lane] = (_Float16)(y0 - (float)h0);
  Yl[n * 128 + lane + 64] = (_Float16)(y1 - (float)h1v);
}

// ---------- dec: f16-split MFMA, G[pq][n][co] = A_pq * Yshift ----------
__global__ __launch_bounds__(256) void k_dec(const _Float16* __restrict__ Yh,
                                             const _Float16* __restrict__ Yl,
                                             const _Float16* __restrict__ Ah,
                                             const _Float16* __restrict__ Al,
                                             float* __restrict__ G) {
  int bxx = blockIdx.x;
  int pq = bxx >> 6, n_t = bxx & 63;
  int w = threadIdx.x >> 6, l = threadIdx.x & 63;
  int ln = l & 15, quad = l >> 4;
  int coW = w * 32;
  int nB = n_t * 32;
  int py = pq / 5, px = pq - py * 5;
  int dy = (py == 0) ? -1 : ((py == 4) ? 1 : 0);
  int dx = (px == 0) ? -1 : ((px == 4) ? 1 : 0);
  int src[2];
#pragma unroll
  for (int s = 0; s < 2; s++) {
    int n = nB + s * 16 + ln;
    int bb = n >> 6, s6 = n & 63;
    int sy = (s6 >> 3) + dy, sx = (s6 & 7) + dx;
    bool ok = ((unsigned)sy < 8u) && ((unsigned)sx < 8u);
    src[s] = ok ? ((bb * 64 + sy * 8 + sx) * 128) : YTAIL;
  }
  int kq = quad * 8;
  f32x4 acc[2][2] = {};
#pragma unroll 2
  for (int ci0 = 0; ci0 < 128; ci0 += 32) {
    const int wbase = (pq * 128 + coW + ln) * 128 + ci0 + kq;
    f16x8 Ah0 = *(const f16x8*)&Ah[wbase];
    f16x8 Al0 = *(const f16x8*)&Al[wbase];
    f16x8 Ah1 = *(const f16x8*)&Ah[wbase + 2048];
    f16x8 Al1 = *(const f16x8*)&Al[wbase + 2048];
    f16x8 Bh[2], Bl[2];
#pragma unroll
    for (int s = 0; s < 2; s++) {
      Bh[s] = *(const f16x8*)&Yh[src[s] + ci0 + kq];
      Bl[s] = *(const f16x8*)&Yl[src[s] + ci0 + kq];
    }
#pragma unroll
    for (int cs = 0; cs < 2; cs++) {
      f16x8 ah = cs ? Ah1 : Ah0;
      f16x8 al = cs ? Al1 : Al0;
#pragma unroll
      for (int s = 0; s < 2; s++) {
        acc[cs][s] = __builtin_amdgcn_mfma_f32_16x16x32_f16(al, Bh[s], acc[cs][s], 0, 0, 0);
        acc[cs][s] = __builtin_amdgcn_mfma_f32_16x16x32_f16(ah, Bl[s], acc[cs][s], 0, 0, 0);
        acc[cs][s] = __builtin_amdgcn_mfma_f32_16x16x32_f16(ah, Bh[s], acc[cs][s], 0, 0, 0);
      }
    }
  }
#pragma unroll
  for (int cs = 0; cs < 2; cs++)
#pragma unroll
    for (int s = 0; s < 2; s++) {
      int site = nB + s * 16 + ln;
      float4 g = make_float4(acc[cs][s][0], acc[cs][s][1], acc[cs][s][2], acc[cs][s][3]);
      *(float4*)&G[(pq * 2048 + site) * 128 + coW + cs * 16 + quad * 4] = g;
    }
}

// ---------- out: combine G per class, bias+relu, 1x1 conv to 3ch, splat ------
__global__ __launch_bounds__(256) void k_out(const float* __restrict__ G,
                                             const float* __restrict__ bc1,
                                             const float* __restrict__ w3,
                                             const float* __restrict__ b3,
                                             float* __restrict__ xhat,
                                             const float* __restrict__ loss_acc,
                                             float* __restrict__ out_loss) {
  __shared__ float Tb[9][128];
  __shared__ float part[9][3][8];
  __shared__ float vals[9][3];
  int bj = blockIdx.x, bi = blockIdx.y, b = blockIdx.z;
  int s = bi * 8 + bj;
  int n = b * 64 + s;
  int tid = threadIdx.x;
  if (bj == 0 && bi == 0 && b == 0 && tid == 0)
    out_loss[0] = loss_acc[0] * 1.25f / 131072.0f;
  int co = tid & 127, h = tid >> 7;
  const int rset[3][2] = {{0, 1}, {2, 2}, {3, 4}};
  const int rcnt[3] = {2, 1, 2};
  for (int cls = h; cls < 9; cls += 2) {
    int r = cls / 3, c = cls - r * 3;
    float sum = bc1[co];
    for (int iy = 0; iy < rcnt[r]; iy++) {
      int py = rset[r][iy];
      for (int ix = 0; ix < rcnt[c]; ix++) {
        int px = rset[c][ix];
        sum += G[((py * 5 + px) * 2048 + n) * 128 + co];
      }
    }
    Tb[cls][co] = fmaxf(sum, 0.f);
  }
  __syncthreads();
  if (tid < 216) {
    int cls = tid / 24, rem = tid - cls * 24;
    int cc = rem >> 3, seg = rem & 7;
    float ss = 0.f;
#pragma unroll
    for (int d = 0; d < 16; d++) ss = fmaf(w3[cc * 128 + seg * 16 + d], Tb[cls][seg * 16 + d], ss);
    part[cls][cc][seg] = ss;
  }
  __syncthreads();
  if (tid < 27) {
    int cls = tid / 3, cc = tid - cls * 3;
    float ss = b3[cc];
#pragma unroll
    for (int seg = 0; seg < 8; seg++) ss += part[cls][cc][seg];
    vals[cls][cc] = ss;
  }
  __syncthreads();
  for (int i = tid; i < 768; i += 256) {
    int cc = i >> 8, p = i & 255;
    int ry = p >> 4, rx = p & 15;
    int rcls = (ry == 0) ? 0 : ((ry == 15) ? 2 : 1);
    int ccls = (rx == 0) ? 0 : ((rx == 15) ? 2 : 1);
    xhat[((b * 3 + cc) * 128 + bi * 16 + ry) * 128 + bj * 16 + rx] =
        vals[rcls * 3 + ccls][cc];
  }
}

extern "C" void kernel_launch(void* const* d_in, const int* in_sizes, int n_in,
                              void* d_out, int out_size, void* d_ws, size_t ws_size,
                              hipStream_t stream) {
  const float* x   = (const float*)d_in[0];
  const float* w1  = (const float*)d_in[1];
  const float* b1  = (const float*)d_in[2];
  const float* w2  = (const float*)d_in[3];
  const float* b2  = (const float*)d_in[4];
  const float* wp  = (const float*)d_in[5];
  const float* pb  = (const float*)d_in[6];
  const float* cb  = (const float*)d_in[7];
  const float* wd  = (const float*)d_in[8];
  const float* db  = (const float*)d_in[9];
  const float* wc1 = (const float*)d_in[10];
  const float* bc1 = (const float*)d_in[11];
  const float* wc2 = (const float*)d_in[12];
  const float* bc2 = (const float*)d_in[13];
  float* out = (float*)d_out;
  float* ws  = (float*)d_ws;

  // workspace (float offsets):
  _Float16* h1h = (_Float16*)(ws);             // [0, 8388640)  (h1l = h1h + H1PL)
  _Float16* h1l = (_Float16*)(ws + 8388640);   // [8388640, 16777280)
  float* h2     = ws + 16777280;               // 4194304
  _Float16* Wh  = (_Float16*)(ws + 20971584);  // 73728 fl
  _Float16* Wl  = (_Float16*)(ws + 21045312);  // 73728 fl
  float* w1t    = ws + 21119040;               // 3456
  float* wpT    = ws + 21122496;               // 8192
  float* wdT    = ws + 21130688;               // 8192
  float* cbT    = ws + 21138880;               // 32768
  _Float16* Ahd = (_Float16*)(ws + 21171648);  // 204800 fl
  _Float16* Ald = (_Float16*)(ws + 21376448);  // 204800 fl -> end 21581248
  // overlays inside dead h1h/h1l region (valid after conv2):
  float* G       = ws;                         // [0, 6553600)
  _Float16* Yh   = (_Float16*)(ws + 6553600);  // 131136 fl (2049*128 f16)
  _Float16* Yl   = (_Float16*)(ws + 6684736);  // 131136 fl
  float* lossacc = ws + 6815872;               // 1

  float* o_xhat = out;
  float* o_idx  = out + 1572864;
  float* o_loss = out + 1574912;
  float* o_ze   = out + 1574913;

  k_prep<<<dim3(910), 256, 0, stream>>>(w2, w1, wp, wd, wc1, cb,
                                        w1t, wpT, wdT, cbT, Ahd, Ald, Wh, Wl, h1h, h1l);
  k_conv1<<<dim3(4, 16, 32), 256, 0, stream>>>(x, w1t, b1, h1h, h1l);
  k_conv2<<<dim3(512), 256, 0, stream>>>(h1h, Wh, Wl, b2, h2);
  k_poolproj<<<dim3(64), 256, 0, stream>>>(h2, wpT, pb, o_ze, lossacc);
  k_vqdproj<<<dim3(2048), 64, 0, stream>>>(o_ze, cbT, cb, wdT, db, o_idx, Yh, Yl, lossacc);
  k_dec<<<dim3(1600), 256, 0, stream>>>(Yh, Yl, Ahd, Ald, G);
  k_out<<<dim3(8, 8, 32), 256, 0, stream>>>(G, bc1, wc2, bc2, o_xhat, lossacc, o_loss);
}

// Round 9
// 280.577 us; speedup vs baseline: 1.6369x; 1.0013x over previous
//
#include <hip/hip_runtime.h>
#include <math.h>

// ---------------------------------------------------------------------------
// VQVAE forward. v9: conv2 stages full 32-ci x 5-row B tile (41.6 KB LDS, 8
// barriers total); prep fully coalesced (LDS tile transposes); poolproj on
// 128 blocks. f16-split MFMA everywhere (C = Ah*Bh + Ah*Bl + Al*Bh).
// ---------------------------------------------------------------------------

typedef _Float16 f16x8 __attribute__((ext_vector_type(8)));
typedef float f32x4 __attribute__((ext_vector_type(4)));

#define H1N 16777216        // elements per h1 plane; zero tail after
#define H1PL 16777280       // f16 offset between h1h and h1l planes
#define YTAIL (2048 * 128)  // zero page in Yh/Yl for OOB shifts

// ---------- prep: A-agg (0..127), W-split (128..143), cbT (144..151), misc --
__global__ __launch_bounds__(256) void k_prep(const float* __restrict__ w2,
                                              const float* __restrict__ w1,
                                              const float* __restrict__ wp,
                                              const float* __restrict__ wd,
                                              const float* __restrict__ wd1,
                                              const float* __restrict__ cb,
                                              float* __restrict__ w1t,
                                              float* __restrict__ wpT,
                                              float* __restrict__ wdT,
                                              float* __restrict__ cbT,
                                              _Float16* __restrict__ Ah,
                                              _Float16* __restrict__ Al,
                                              _Float16* __restrict__ Wh,
                                              _Float16* __restrict__ Wl,
                                              _Float16* __restrict__ h1h,
                                              _Float16* __restrict__ h1l) {
  int bx = blockIdx.x, tid = threadIdx.x;
  if (bx < 128) {  // ---- A aggregation, block = co, lanes = ci (writes coalesced)
    __shared__ float wrow[1152];
    int co = bx;
    for (int i = tid; i < 1152; i += 256) wrow[i] = wd1[co * 1152 + i];
    __syncthreads();
    if (tid < 128) {
      int ci = tid;
      float w[9];
#pragma unroll
      for (int t = 0; t < 9; t++) w[t] = wrow[ci * 9 + t];
      float rx[3][5];
#pragma unroll
      for (int ky = 0; ky < 3; ky++) {
        float a0 = w[ky * 3 + 0], a1 = w[ky * 3 + 1], a2 = w[ky * 3 + 2];
        rx[ky][0] = a0; rx[ky][1] = a1 + a2; rx[ky][2] = a0 + a1 + a2;
        rx[ky][3] = a0 + a1; rx[ky][4] = a2;
      }
#pragma unroll
      for (int px = 0; px < 5; px++) {
        float s0 = rx[0][px], s1 = rx[1][px], s2 = rx[2][px];
        float ry[5];
        ry[0] = s0; ry[1] = s1 + s2; ry[2] = s0 + s1 + s2; ry[3] = s0 + s1; ry[4] = s2;
#pragma unroll
        for (int py = 0; py < 5; py++) {
          int pq = py * 5 + px;
          float v = ry[py];
          _Float16 h = (_Float16)v;
          int o = (pq * 128 + co) * 128 + ci;
          Ah[o] = h;
          Al[o] = (_Float16)(v - (float)h);
        }
      }
    }
    return;
  }
  if (bx < 144) {  // ---- W f16-split: 8 co per block, LDS-staged, coalesced RW
    __shared__ float wst[9216];
    int co0 = (bx - 128) * 8;
    for (int i = tid; i < 9216; i += 256) wst[i] = w2[co0 * 1152 + i];
    __syncthreads();
    for (int i = tid; i < 9216; i += 256) {
      int co = i / 1152, r = i - co * 1152;
      int tap = r >> 7, ci = r & 127;
      float v = wst[co * 1152 + ci * 9 + tap];
      _Float16 h = (_Float16)v;
      int o = (tap * 128 + co0 + co) * 128 + ci;
      Wh[o] = h;
      Wl[o] = (_Float16)(v - (float)h);
    }
    return;
  }
  if (bx < 152) {  // ---- cbT tile transpose (64 k x 64 d), padded LDS
    __shared__ float cbs[64 * 65];
    int k0 = (bx - 144) * 64;
    for (int i = tid; i < 4096; i += 256) {
      int k = i >> 6, d = i & 63;
      cbs[k * 65 + d] = cb[(k0 + k) * 64 + d];
    }
    __syncthreads();
    for (int i = tid; i < 4096; i += 256) {
      int d = i >> 6, k = i & 63;
      cbT[d * 512 + k0 + k] = cbs[k * 65 + d];
    }
    return;
  }
  // ---- misc small transposes + h1 zero tails (writes lane-contiguous)
  for (int i = tid; i < 3456; i += 256) {  // w1t[t][co] = w1[co][t]
    int co = i & 127, t = i >> 7;
    w1t[t * 128 + co] = w1[co * 27 + t];
  }
  for (int i = tid; i < 8192; i += 256) {  // wpT[k][d] = wp[d][k]
    int d = i & 63, k = i >> 6;
    wpT[k * 64 + d] = wp[d * 128 + k];
  }
  for (int i = tid; i < 8192; i += 256) {  // wdT[d][co] = wd[co][d]
    int co = i & 127, d = i >> 7;
    wdT[d * 128 + co] = wd[co * 64 + d];
  }
  if (tid < 64) {
    h1h[H1N + tid] = (_Float16)0.f;
    h1l[H1N + tid] = (_Float16)0.f;
  }
}

// ---------- conv1: (32,3,128,128) -> h1 f16-split [g][b][oh][ow][8ci] -------
__global__ __launch_bounds__(256) void k_conv1(const float* __restrict__ x,
                                               const float* __restrict__ w1t,
                                               const float* __restrict__ b1,
                                               _Float16* __restrict__ h1h,
                                               _Float16* __restrict__ h1l) {
  __shared__ float E[3][9][68];
  __shared__ float O[3][9][68];
  int co_t = blockIdx.x, oh_t = blockIdx.y, b = blockIdx.z;
  int oh0 = oh_t * 4;
  int tid = threadIdx.x;
  int wv = __builtin_amdgcn_readfirstlane(tid >> 6);
  int l = tid & 63;
  int coB = co_t * 32 + wv * 8;

  for (int idx = tid; idx < 1728; idx += 256) {
    int p = idx & 63, r = idx >> 6;
    int ci = r / 9, lr = r - ci * 9;
    int ih = 2 * oh0 - 1 + lr;
    float2 v = make_float2(0.f, 0.f);
    if ((unsigned)ih < 128u)
      v = *(const float2*)&x[((b * 3 + ci) * 128 + ih) * 128 + 2 * p];
    E[ci][lr][p] = v.x;
    O[ci][lr][p + 1] = v.y;
  }
  if (tid < 27) {
    int ci = tid / 9, lr = tid - ci * 9;
    O[ci][lr][0] = 0.f;
  }
  __syncthreads();

  int ohl = l >> 4, ow0 = (l & 15) * 4;
  int oh = oh0 + ohl;
  float4 acc[8];
#pragma unroll
  for (int q = 0; q < 8; q++) {
    float bv = b1[coB + q];
    acc[q] = make_float4(bv, bv, bv, bv);
  }
#pragma unroll
  for (int ci = 0; ci < 3; ci++) {
#pragma unroll
    for (int ky = 0; ky < 3; ky++) {
      int lr = 2 * ohl + ky;
      float4 ev = *(float4*)&E[ci][lr][ow0];
      float4 od = *(float4*)&O[ci][lr][ow0];
      float o4 = O[ci][lr][ow0 + 4];
      const float* wr = w1t + (ci * 9 + ky * 3) * 128 + coB;
#pragma unroll
      for (int q = 0; q < 8; q++) {
        float wa = wr[q], wb = wr[128 + q], wc = wr[256 + q];
        acc[q].x = fmaf(wa, od.x, acc[q].x);
        acc[q].x = fmaf(wb, ev.x, acc[q].x);
        acc[q].x = fmaf(wc, od.y, acc[q].x);
        acc[q].y = fmaf(wa, od.y, acc[q].y);
        acc[q].y = fmaf(wb, ev.y, acc[q].y);
        acc[q].y = fmaf(wc, od.z, acc[q].y);
        acc[q].z = fmaf(wa, od.z, acc[q].z);
        acc[q].z = fmaf(wb, ev.z, acc[q].z);
        acc[q].z = fmaf(wc, od.w, acc[q].z);
        acc[q].w = fmaf(wa, od.w, acc[q].w);
        acc[q].w = fmaf(wb, ev.w, acc[q].w);
        acc[q].w = fmaf(wc, o4,   acc[q].w);
      }
    }
  }
  int g = coB >> 3;
  int pbase = ((g * 32 + b) * 64 + oh) * 64;
#pragma unroll
  for (int oi = 0; oi < 4; oi++) {
    f16x8 hv, lv;
#pragma unroll
    for (int q = 0; q < 8; q++) {
      float v = fmaxf(((const float*)&acc[q])[oi], 0.f);
      _Float16 h = (_Float16)v;
      float rem = v - (float)h;
      hv[q] = h;
      lv[q] = (_Float16)rem;
    }
    int base = (pbase + ow0 + oi) * 8;
    *(f16x8*)&h1h[base] = hv;
    *(f16x8*)&h1l[base] = lv;
  }
}

// ---------- conv2: f16-split MFMA; block = 128co x 64px, 4 fat LDS steps ----
// grid 512 = (b(32) x ohp(16)); block 256 = 4 waves (wave w: co 32w..32w+31).
// LDS B: chunk c = ((g*5 + r)*2 + pl)*65 + (ph? 33+u : u), g=ci-group(4),
//   r=row(5: ih=2*oh0-1+r), pl=plane, ph=0: iw=2u-1, ph=1: iw=2u. 16 B/chunk.
__global__ __launch_bounds__(256) void k_conv2(const _Float16* __restrict__ h1h,
                                               const _Float16* __restrict__ Wh,
                                               const _Float16* __restrict__ Wl,
                                               const float* __restrict__ b2,
                                               float* __restrict__ h2) {
  __shared__ _Float16 Bbuf[20800];  // 2600 chunks x 16 B = 41600 B
  int bx = blockIdx.x;
  int b = bx >> 4, ohp = bx & 15;
  int oh0 = ohp * 2;
  int tid = threadIdx.x;
  int w = tid >> 6, l = tid & 63;
  int ln = l & 15, quad = l >> 4;
  int coW = w * 32;
  int kq = quad * 8;
  f32x4 acc[2][4] = {};  // [cs][s]

  for (int ci0 = 0; ci0 < 128; ci0 += 32) {
    __syncthreads();
    for (int c = tid; c < 2600; c += 256) {
      int q = c / 65, rem = c - q * 65;
      int ph = rem >= 33;
      int u = ph ? rem - 33 : rem;
      int pl = q & 1, t = q >> 1;
      int r = t % 5, g = t / 5;
      int iw = ph ? 2 * u : 2 * u - 1;
      int ih = 2 * oh0 - 1 + r;
      bool ok = (ih >= 0) && (iw >= 0) && (iw < 64);
      int src = pl * H1PL + (ok ? ((((ci0 >> 3) + g) * 32 + b) * 64 + ih) * 512 + iw * 8
                                : H1N);
      *(f16x8*)&Bbuf[c * 8] = *(const f16x8*)&h1h[src];
    }
    __syncthreads();
    for (int ky = 0; ky < 3; ky++) {
#pragma unroll
      for (int kx = 0; kx < 3; kx++) {
        int tap = ky * 3 + kx;
        const int wbase = (tap * 128 + coW + ln) * 128 + ci0 + kq;
        f16x8 Ah0 = *(const f16x8*)&Wh[wbase];
        f16x8 Al0 = *(const f16x8*)&Wl[wbase];
        f16x8 Ah1 = *(const f16x8*)&Wh[wbase + 2048];  // +16 co
        f16x8 Al1 = *(const f16x8*)&Wl[wbase + 2048];
#pragma unroll
        for (int s = 0; s < 4; s++) {
          int owl = (s & 1) * 16 + ln;
          int r = 2 * (s >> 1) + ky;
          int base = ((quad * 5 + r) * 2) * 65;
          int uoff = (kx == 1) ? (33 + owl) : (owl + (kx == 2));
          f16x8 Bh = *(const f16x8*)&Bbuf[(base + uoff) * 8];
          f16x8 Bl = *(const f16x8*)&Bbuf[(base + 65 + uoff) * 8];
          acc[0][s] = __builtin_amdgcn_mfma_f32_16x16x32_f16(Al0, Bh, acc[0][s], 0, 0, 0);
          acc[0][s] = __builtin_amdgcn_mfma_f32_16x16x32_f16(Ah0, Bl, acc[0][s], 0, 0, 0);
          acc[0][s] = __builtin_amdgcn_mfma_f32_16x16x32_f16(Ah0, Bh, acc[0][s], 0, 0, 0);
          acc[1][s] = __builtin_amdgcn_mfma_f32_16x16x32_f16(Al1, Bh, acc[1][s], 0, 0, 0);
          acc[1][s] = __builtin_amdgcn_mfma_f32_16x16x32_f16(Ah1, Bl, acc[1][s], 0, 0, 0);
          acc[1][s] = __builtin_amdgcn_mfma_f32_16x16x32_f16(Ah1, Bh, acc[1][s], 0, 0, 0);
        }
      }
    }
  }
  // epilogue: C row = co (quad*4+reg), col = px (lane&15)
#pragma unroll
  for (int cs = 0; cs < 2; cs++)
#pragma unroll
    for (int s = 0; s < 4; s++) {
      int oh = oh0 + (s >> 1);
      int ow = (s & 1) * 16 + ln;
#pragma unroll
      for (int r = 0; r < 4; r++) {
        int co = coW + cs * 16 + quad * 4 + r;
        h2[((b * 128 + co) * 32 + oh) * 32 + ow] = fmaxf(acc[cs][s][r] + b2[co], 0.f);
      }
    }
}

// ---------- pool(4x4 mean) + proj(1x1,128->64); grid 128 (b x quarter) ------
__global__ __launch_bounds__(256) void k_poolproj(const float* __restrict__ h2,
                                                  const float* __restrict__ wpT,
                                                  const float* __restrict__ pb,
                                                  float* __restrict__ z_e_out,
                                                  float* __restrict__ lossacc) {
  __shared__ float hp[128][16];
  __shared__ float Ws[128][64];
  int bx = blockIdx.x, tid = threadIdx.x;
  int b = bx >> 2, quarter = bx & 3;
  if (bx == 0 && tid == 0) lossacc[0] = 0.f;
  for (int i = tid; i < 8192; i += 256) Ws[i >> 6][i & 63] = wpT[i];
  for (int i = tid; i < 2048; i += 256) {
    int ci = i >> 4, pl = i & 15;
    int pi = quarter * 16 + pl;
    int bi = pi >> 3, bj = pi & 7;
    const float* src = &h2[((b * 128 + ci) * 32 + bi * 4) * 32 + bj * 4];
    float4 r0 = *(const float4*)src;
    float4 r1 = *(const float4*)(src + 32);
    float4 r2 = *(const float4*)(src + 64);
    float4 r3 = *(const float4*)(src + 96);
    float s = r0.x + r0.y + r0.z + r0.w + r1.x + r1.y + r1.z + r1.w +
              r2.x + r2.y + r2.z + r2.w + r3.x + r3.y + r3.z + r3.w;
    hp[ci][pl] = s * 0.0625f;
  }
  __syncthreads();
  int d = tid >> 2, s0 = (tid & 3) * 4;
  float4 acc = make_float4(0.f, 0.f, 0.f, 0.f);
  for (int k = 0; k < 128; k++) {
    float a = Ws[k][d];
    float4 h = *(float4*)&hp[k][s0];
    acc.x = fmaf(a, h.x, acc.x);
    acc.y = fmaf(a, h.y, acc.y);
    acc.z = fmaf(a, h.z, acc.z);
    acc.w = fmaf(a, h.w, acc.w);
  }
  float bv = pb[d];
  float4 r4 = make_float4(acc.x + bv, acc.y + bv, acc.z + bv, acc.w + bv);
  *(float4*)&z_e_out[(b * 64 + d) * 64 + quarter * 16 + s0] = r4;
}

// ---------- VQ argmin + loss + dproj -> Yh/Yl f16 planes; grid 2048 ----------
__global__ __launch_bounds__(64) void k_vqdproj(const float* __restrict__ z_e,
                                                const float* __restrict__ cbT,
                                                const float* __restrict__ cb,
                                                const float* __restrict__ wdT,
                                                const float* __restrict__ db,
                                                float* __restrict__ idx_f,
                                                _Float16* __restrict__ Yh,
                                                _Float16* __restrict__ Yl,
                                                float* __restrict__ loss_acc) {
  __shared__ float zs[64];
  int n = blockIdx.x, lane = threadIdx.x;
  int b = n >> 6, pi = n & 63;
  zs[lane] = z_e[(b * 64 + lane) * 64 + pi];
  if (n == 0) {  // zero tail page for shifted reads in k_dec
    Yh[YTAIL + lane] = (_Float16)0.f;
    Yh[YTAIL + 64 + lane] = (_Float16)0.f;
    Yl[YTAIL + lane] = (_Float16)0.f;
    Yl[YTAIL + 64 + lane] = (_Float16)0.f;
  }
  __syncthreads();
  double best = 1e300;
  int bi = 0;
#pragma unroll 2
  for (int j = 0; j < 8; j++) {
    int k = j * 64 + lane;
    double a0 = 0.0, a1 = 0.0, a2 = 0.0, a3 = 0.0;
#pragma unroll 4
    for (int d = 0; d < 64; d += 4) {
      double f0 = (double)zs[d] - (double)cbT[d * 512 + k];
      double f1 = (double)zs[d + 1] - (double)cbT[(d + 1) * 512 + k];
      double f2 = (double)zs[d + 2] - (double)cbT[(d + 2) * 512 + k];
      double f3 = (double)zs[d + 3] - (double)cbT[(d + 3) * 512 + k];
      a0 = fma(f0, f0, a0);
      a1 = fma(f1, f1, a1);
      a2 = fma(f2, f2, a2);
      a3 = fma(f3, f3, a3);
    }
    double acc = (a0 + a1) + (a2 + a3);
    if (acc < best) { best = acc; bi = k; }
  }
  for (int m = 1; m < 64; m <<= 1) {
    double ob = __shfl_xor(best, m, 64);
    int oi = __shfl_xor(bi, m, 64);
    if (ob < best || (ob == best && oi < bi)) { best = ob; bi = oi; }
  }
  float zq_l = cb[bi * 64 + lane];
  float e = zq_l - zs[lane];
  float sq = e * e;
  for (int m = 1; m < 64; m <<= 1) sq += __shfl_xor(sq, m, 64);
  if (lane == 0) {
    idx_f[n] = (float)bi;
    atomicAdd(loss_acc, sq);
  }
  __syncthreads();
  zs[lane] = zq_l;
  __syncthreads();
  float a0 = db[lane], a1 = db[lane + 64];
#pragma unroll 4
  for (int d = 0; d < 64; d++) {
    float z = zs[d];
    a0 = fmaf(wdT[d * 128 + lane], z, a0);
    a1 = fmaf(wdT[d * 128 + lane + 64], z, a1);
  }
  float y0 = fmaxf(a0, 0.f), y1 = fmaxf(a1, 0.f);
  _Float16 h0 = (_Float16)y0, h1v = (_Float16)y1;
  Yh[n * 128 + lane] = h0;
  Yh[n * 128 + lane + 64] = h1v;
  Yl[n * 128 + lane] = (_Float16)(y0 - (float)h0);
  Yl[n * 128 + lane + 64] = (_Float16)(y1 - (float)h1v);
}

// ---------- dec: f16-split MFMA, G[pq][n][co] = A_pq * Yshift ----------
__global__ __launch_bounds__(256) void k_dec(const _Float16* __restrict__ Yh,
                                             const _Float16* __restrict__ Yl,
                                             const _Float16* __restrict__ Ah,
                                             const _Float16* __restrict__ Al,
                                             float* __restrict__ G) {
  int bxx = blockIdx.x;
  int pq = bxx >> 6, n_t = bxx & 63;
  int w = threadIdx.x >> 6, l = threadIdx.x & 63;
  int ln = l & 15, quad = l >> 4;
  int coW = w * 32;
  int nB = n_t * 32;
  int py = pq / 5, px = pq - py * 5;
  int dy = (py == 0) ? -1 : ((py == 4) ? 1 : 0);
  int dx = (px == 0) ? -1 : ((px == 4) ? 1 : 0);
  int src[2];
#pragma unroll
  for (int s = 0; s < 2; s++) {
    int n = nB + s * 16 + ln;
    int bb = n >> 6, s6 = n & 63;
    int sy = (s6 >> 3) + dy, sx = (s6 & 7) + dx;
    bool ok = ((unsigned)sy < 8u) && ((unsigned)sx < 8u);
    src[s] = ok ? ((bb * 64 + sy * 8 + sx) * 128) : YTAIL;
  }
  int kq = quad * 8;
  f32x4 acc[2][2] = {};
#pragma unroll 2
  for (int ci0 = 0; ci0 < 128; ci0 += 32) {
    const int wbase = (pq * 128 + coW + ln) * 128 + ci0 + kq;
    f16x8 Ah0 = *(const f16x8*)&Ah[wbase];
    f16x8 Al0 = *(const f16x8*)&Al[wbase];
    f16x8 Ah1 = *(const f16x8*)&Ah[wbase + 2048];
    f16x8 Al1 = *(const f16x8*)&Al[wbase + 2048];
    f16x8 Bh[2], Bl[2];
#pragma unroll
    for (int s = 0; s < 2; s++) {
      Bh[s] = *(const f16x8*)&Yh[src[s] + ci0 + kq];
      Bl[s] = *(const f16x8*)&Yl[src[s] + ci0 + kq];
    }
#pragma unroll
    for (int cs = 0; cs < 2; cs++) {
      f16x8 ah = cs ? Ah1 : Ah0;
      f16x8 al = cs ? Al1 : Al0;
#pragma unroll
      for (int s = 0; s < 2; s++) {
        acc[cs][s] = __builtin_amdgcn_mfma_f32_16x16x32_f16(al, Bh[s], acc[cs][s], 0, 0, 0);
        acc[cs][s] = __builtin_amdgcn_mfma_f32_16x16x32_f16(ah, Bl[s], acc[cs][s], 0, 0, 0);
        acc[cs][s] = __builtin_amdgcn_mfma_f32_16x16x32_f16(ah, Bh[s], acc[cs][s], 0, 0, 0);
      }
    }
  }
#pragma unroll
  for (int cs = 0; cs < 2; cs++)
#pragma unroll
    for (int s = 0; s < 2; s++) {
      int site = nB + s * 16 + ln;
      float4 g = make_float4(acc[cs][s][0], acc[cs][s][1], acc[cs][s][2], acc[cs][s][3]);
      *(float4*)&G[(pq * 2048 + site) * 128 + coW + cs * 16 + quad * 4] = g;
    }
}

// ---------- out: combine G per class, bias+relu, 1x1 conv to 3ch, splat ------
__global__ __launch_bounds__(256) void k_out(const float* __restrict__ G,
                                             const float* __restrict__ bc1,
                                             const float* __restrict__ w3,
                                             const float* __restrict__ b3,
                                             float* __restrict__ xhat,
                                             const float* __restrict__ loss_acc,
                                             float* __restrict__ out_loss) {
  __shared__ float Tb[9][128];
  __shared__ float part[9][3][8];
  __shared__ float vals[9][3];
  int bj = blockIdx.x, bi = blockIdx.y, b = blockIdx.z;
  int s = bi * 8 + bj;
  int n = b * 64 + s;
  int tid = threadIdx.x;
  if (bj == 0 && bi == 0 && b == 0 && tid == 0)
    out_loss[0] = loss_acc[0] * 1.25f / 131072.0f;
  int co = tid & 127, h = tid >> 7;
  const int rset[3][2] = {{0, 1}, {2, 2}, {3, 4}};
  const int rcnt[3] = {2, 1, 2};
  for (int cls = h; cls < 9; cls += 2) {
    int r = cls / 3, c = cls - r * 3;
    float sum = bc1[co];
    for (int iy = 0; iy < rcnt[r]; iy++) {
      int py = rset[r][iy];
      for (int ix = 0; ix < rcnt[c]; ix++) {
        int px = rset[c][ix];
        sum += G[((py * 5 + px) * 2048 + n) * 128 + co];
      }
    }
    Tb[cls][co] = fmaxf(sum, 0.f);
  }
  __syncthreads();
  if (tid < 216) {
    int cls = tid / 24, rem = tid - cls * 24;
    int cc = rem >> 3, seg = rem & 7;
    float ss = 0.f;
#pragma unroll
    for (int d = 0; d < 16; d++) ss = fmaf(w3[cc * 128 + seg * 16 + d], Tb[cls][seg * 16 + d], ss);
    part[cls][cc][seg] = ss;
  }
  __syncthreads();
  if (tid < 27) {
    int cls = tid / 3, cc = tid - cls * 3;
    float ss = b3[cc];
#pragma unroll
    for (int seg = 0; seg < 8; seg++) ss += part[cls][cc][seg];
    vals[cls][cc] = ss;
  }
  __syncthreads();
  for (int i = tid; i < 768; i += 256) {
    int cc = i >> 8, p = i & 255;
    int ry = p >> 4, rx = p & 15;
    int rcls = (ry == 0) ? 0 : ((ry == 15) ? 2 : 1);
    int ccls = (rx == 0) ? 0 : ((rx == 15) ? 2 : 1);
    xhat[((b * 3 + cc) * 128 + bi * 16 + ry) * 128 + bj * 16 + rx] =
        vals[rcls * 3 + ccls][cc];
  }
}

extern "C" void kernel_launch(void* const* d_in, const int* in_sizes, int n_in,
                              void* d_out, int out_size, void* d_ws, size_t ws_size,
                              hipStream_t stream) {
  const float* x   = (const float*)d_in[0];
  const float* w1  = (const float*)d_in[1];
  const float* b1  = (const float*)d_in[2];
  const float* w2  = (const float*)d_in[3];
  const float* b2  = (const float*)d_in[4];
  const float* wp  = (const float*)d_in[5];
  const float* pb  = (const float*)d_in[6];
  const float* cb  = (const float*)d_in[7];
  const float* wd  = (const float*)d_in[8];
  const float* db  = (const float*)d_in[9];
  const float* wc1 = (const float*)d_in[10];
  const float* bc1 = (const float*)d_in[11];
  const float* wc2 = (const float*)d_in[12];
  const float* bc2 = (const float*)d_in[13];
  float* out = (float*)d_out;
  float* ws  = (float*)d_ws;

  // workspace (float offsets):
  _Float16* h1h = (_Float16*)(ws);             // [0, 8388640)  (h1l = h1h + H1PL)
  _Float16* h1l = (_Float16*)(ws + 8388640);   // [8388640, 16777280)
  float* h2     = ws + 16777280;               // 4194304
  _Float16* Wh  = (_Float16*)(ws + 20971584);  // 73728 fl
  _Float16* Wl  = (_Float16*)(ws + 21045312);  // 73728 fl
  float* w1t    = ws + 21119040;               // 3456
  float* wpT    = ws + 21122496;               // 8192
  float* wdT    = ws + 21130688;               // 8192
  float* cbT    = ws + 21138880;               // 32768
  _Float16* Ahd = (_Float16*)(ws + 21171648);  // 204800 fl
  _Float16* Ald = (_Float16*)(ws + 21376448);  // 204800 fl -> end 21581248
  // overlays inside dead h1h/h1l region (valid after conv2):
  float* G       = ws;                         // [0, 6553600)
  _Float16* Yh   = (_Float16*)(ws + 6553600);  // 131136 fl (2049*128 f16)
  _Float16* Yl   = (_Float16*)(ws + 6684736);  // 131136 fl
  float* lossacc = ws + 6815872;               // 1

  float* o_xhat = out;
  float* o_idx  = out + 1572864;
  float* o_loss = out + 1574912;
  float* o_ze   = out + 1574913;

  k_prep<<<dim3(153), 256, 0, stream>>>(w2, w1, wp, wd, wc1, cb,
                                        w1t, wpT, wdT, cbT, Ahd, Ald, Wh, Wl, h1h, h1l);
  k_conv1<<<dim3(4, 16, 32), 256, 0, stream>>>(x, w1t, b1, h1h, h1l);
  k_conv2<<<dim3(512), 256, 0, stream>>>(h1h, Wh, Wl, b2, h2);
  k_poolproj<<<dim3(128), 256, 0, stream>>>(h2, wpT, pb, o_ze, lossacc);
  k_vqdproj<<<dim3(2048), 64, 0, stream>>>(o_ze, cbT, cb, wdT, db, o_idx, Yh, Yl, lossacc);
  k_dec<<<dim3(1600), 256, 0, stream>>>(Yh, Yl, Ahd, Ald, G);
  k_out<<<dim3(8, 8, 32), 256, 0, stream>>>(G, bc1, wc2, bc2, o_xhat, lossacc, o_loss);
}